// Round 6
// baseline (1238.044 us; speedup 1.0000x reference)
//
#include <hip/hip_runtime.h>
#include <cstddef>
#include <cstdint>
#include <math.h>

#define BB   4
#define TT   2048
#define CCH  1024
#define HH   16
#define DD   64
#define CSZ  16
#define NTC  128
#define EPSF 1e-5f
#define WVS  8

typedef __attribute__((ext_vector_type(8))) short bf16x8;
typedef __attribute__((ext_vector_type(4))) float f32x4;

// ---------- split-float helpers: f32 ≈ hi(bf16) + lo(bf16), packed (hi | lo<<16) ----------
__device__ __forceinline__ uint32_t pack_split(float f) {
  uint32_t b = __float_as_uint(f);
  uint32_t uh = (b + 0x7fffu + ((b >> 16) & 1u)) >> 16;   // RNE bf16 of f
  float fh = __uint_as_float(uh << 16);
  float r = f - fh;
  return uh | (__float_as_uint(r) & 0xffff0000u);          // lo = trunc bf16 of residual
}
__device__ __forceinline__ float unpack_f(uint32_t u) {
  return __uint_as_float(u << 16) + __uint_as_float(u & 0xffff0000u);
}

// Wave64 sum via DPP (VALU pipe, not LDS pipe).
__device__ __forceinline__ float wave_sum(float x) {
  float v = x;
  v += __int_as_float(__builtin_amdgcn_update_dpp(0, __float_as_int(v), 0x111, 0xf, 0xf, true));
  v += __int_as_float(__builtin_amdgcn_update_dpp(0, __float_as_int(v), 0x112, 0xf, 0xf, true));
  v += __int_as_float(__builtin_amdgcn_update_dpp(0, __float_as_int(v), 0x114, 0xf, 0xf, true));
  v += __int_as_float(__builtin_amdgcn_update_dpp(0, __float_as_int(v), 0x118, 0xf, 0xf, true));
  v += __int_as_float(__builtin_amdgcn_update_dpp(0, __float_as_int(v), 0x142, 0xa, 0xf, true));
  v += __int_as_float(__builtin_amdgcn_update_dpp(0, __float_as_int(v), 0x143, 0xc, 0xf, true));
  return __int_as_float(__builtin_amdgcn_readlane(__float_as_int(v), 63));
}

__device__ __forceinline__ float sigmoidf_(float x) {
  return 1.f / (1.f + expf(-x));
}

// ---------- transpose + split into PLANES: W (KxN f32) -> Whi/Wlo (NxK ushort) ----------
__global__ __launch_bounds__(256) void split_transpose_pl(
    const float* __restrict__ W, unsigned short* __restrict__ Whi,
    unsigned short* __restrict__ Wlo, int K, int N) {
  __shared__ float t[32][33];
  const int n0 = blockIdx.x * 32, k0 = blockIdx.y * 32;
  const int tx = threadIdx.x & 31, ty = threadIdx.x >> 5;  // ty 0..7
#pragma unroll
  for (int i = 0; i < 4; i++)
    t[ty + i * 8][tx] = W[(size_t)(k0 + ty + i * 8) * N + n0 + tx];
  __syncthreads();
#pragma unroll
  for (int i = 0; i < 4; i++) {
    uint32_t ps = pack_split(t[tx][ty + i * 8]);
    size_t off = (size_t)(n0 + ty + i * 8) * K + k0 + tx;
    Whi[off] = (unsigned short)(ps & 0xffffu);
    Wlo[off] = (unsigned short)(ps >> 16);
  }
}

// ---------- split-bf16 MFMA GEMM with plane-staged B and register prefetch ----------
// C = A @ B^T + bias. B given as hi/lo ushort planes (NxK). M,N,K % 128,128,32 == 0.
// AMODE 1: A = packed u32 (hi|lo<<16), lda in u32.  AMODE 2: A = f32, split on the fly.
// acc += Ahi*Bhi + Ahi*Blo + Alo*Bhi (3xbf16 ~ fp32 precision).
template<int AMODE, bool C_PACKED>
__global__ __launch_bounds__(256) void gemm_planes(
    const void* __restrict__ Av, int lda,
    const unsigned short* __restrict__ Bhg,
    const unsigned short* __restrict__ Blg,
    const float* __restrict__ bias, void* __restrict__ Cv,
    int M, int N, int K) {
  __shared__ unsigned short Ahi[128][40];   // pad 32->40: 2-way banks (free)
  __shared__ unsigned short Alo[128][40];
  __shared__ unsigned short Bhi[128][40];
  __shared__ unsigned short Blo[128][40];

  const int tid = threadIdx.x;
  const int row0 = blockIdx.y * 128;
  const int col0 = blockIdx.x * 128;
  const int wv = tid >> 6;
  const int l  = tid & 63;
  const int wr = wv >> 1, wc = wv & 1;     // 2x2 wave grid, 64x64 per wave
  const int lrow = l & 15;
  const int kgrp = (l >> 4) * 8;
  const int sr = tid >> 1;                 // staging row 0..127
  const int sk = (tid & 1) * 16;           // staging k offset 0/16

  f32x4 acc[4][4];
#pragma unroll
  for (int i = 0; i < 4; i++)
#pragma unroll
    for (int j = 0; j < 4; j++) acc[i][j] = (f32x4){0.f, 0.f, 0.f, 0.f};

  uint4 pa[4];    // AMODE1: 16 packed u32. (unused slots in AMODE2)
  float4 pf[4];   // AMODE2: 16 floats
  uint4 pb[4];    // B: [0..1]=hi 32B, [2..3]=lo 32B

  auto load_tile = [&](int k0) {
    if (AMODE == 1) {
      const uint32_t* Ap = (const uint32_t*)Av + (size_t)(row0 + sr) * lda + k0 + sk;
#pragma unroll
      for (int i = 0; i < 4; i++) pa[i] = *(const uint4*)(Ap + i * 4);
    } else {
      const float* Ap = (const float*)Av + (size_t)(row0 + sr) * lda + k0 + sk;
#pragma unroll
      for (int i = 0; i < 4; i++) pf[i] = *(const float4*)(Ap + i * 4);
    }
    const unsigned short* bh = Bhg + (size_t)(col0 + sr) * K + k0 + sk;
    const unsigned short* bl = Blg + (size_t)(col0 + sr) * K + k0 + sk;
    pb[0] = *(const uint4*)bh;  pb[1] = *(const uint4*)(bh + 8);
    pb[2] = *(const uint4*)bl;  pb[3] = *(const uint4*)(bl + 8);
  };

  auto commit_tile = [&]() {
    uint32_t hp[8], lp[8];
    if (AMODE == 1) {
      uint32_t u[16];
#pragma unroll
      for (int i = 0; i < 4; i++) *(uint4*)&u[i * 4] = pa[i];
#pragma unroll
      for (int j = 0; j < 8; j++) {
        hp[j] = (u[2 * j] & 0xffffu) | (u[2 * j + 1] << 16);
        lp[j] = (u[2 * j] >> 16) | (u[2 * j + 1] & 0xffff0000u);
      }
    } else {
      float f[16];
#pragma unroll
      for (int i = 0; i < 4; i++) *(float4*)&f[i * 4] = pf[i];
      uint32_t uh[16], ulr[16];
#pragma unroll
      for (int j = 0; j < 16; j++) {
        uint32_t b = __float_as_uint(f[j]);
        uint32_t h = (b + 0x7fffu + ((b >> 16) & 1u)) >> 16;
        uh[j] = h;
        ulr[j] = __float_as_uint(f[j] - __uint_as_float(h << 16));
      }
#pragma unroll
      for (int j = 0; j < 8; j++) {
        hp[j] = uh[2 * j] | (uh[2 * j + 1] << 16);
        lp[j] = (ulr[2 * j] >> 16) | (ulr[2 * j + 1] & 0xffff0000u);
      }
    }
    *(uint4*)&Ahi[sr][sk]     = *(uint4*)&hp[0];
    *(uint4*)&Ahi[sr][sk + 8] = *(uint4*)&hp[4];
    *(uint4*)&Alo[sr][sk]     = *(uint4*)&lp[0];
    *(uint4*)&Alo[sr][sk + 8] = *(uint4*)&lp[4];
    *(uint4*)&Bhi[sr][sk]     = pb[0];
    *(uint4*)&Bhi[sr][sk + 8] = pb[1];
    *(uint4*)&Blo[sr][sk]     = pb[2];
    *(uint4*)&Blo[sr][sk + 8] = pb[3];
  };

  load_tile(0);
  for (int k0 = 0; k0 < K; k0 += 32) {
    commit_tile();
    __syncthreads();
    if (k0 + 32 < K) load_tile(k0 + 32);   // in flight across the MFMAs below

    bf16x8 bh[4], bl[4];
#pragma unroll
    for (int j = 0; j < 4; j++) {
      bh[j] = *(const bf16x8*)&Bhi[wc * 64 + j * 16 + lrow][kgrp];
      bl[j] = *(const bf16x8*)&Blo[wc * 64 + j * 16 + lrow][kgrp];
    }
#pragma unroll
    for (int i = 0; i < 4; i++) {
      bf16x8 ah = *(const bf16x8*)&Ahi[wr * 64 + i * 16 + lrow][kgrp];
      bf16x8 al = *(const bf16x8*)&Alo[wr * 64 + i * 16 + lrow][kgrp];
#pragma unroll
      for (int j = 0; j < 4; j++) {
        acc[i][j] = __builtin_amdgcn_mfma_f32_16x16x32_bf16(ah, bh[j], acc[i][j], 0, 0, 0);
        acc[i][j] = __builtin_amdgcn_mfma_f32_16x16x32_bf16(ah, bl[j], acc[i][j], 0, 0, 0);
        acc[i][j] = __builtin_amdgcn_mfma_f32_16x16x32_bf16(al, bh[j], acc[i][j], 0, 0, 0);
      }
    }
    __syncthreads();
  }

  // ---- epilogue: C/D layout col=lane&15, row=(lane>>4)*4+reg ----
  const int crow4 = (l >> 4) * 4;
#pragma unroll
  for (int i = 0; i < 4; i++) {
#pragma unroll
    for (int j = 0; j < 4; j++) {
      const int col = col0 + wc * 64 + j * 16 + lrow;
      const float bv = bias[col];
      const int rowb = row0 + wr * 64 + i * 16 + crow4;
#pragma unroll
      for (int r = 0; r < 4; r++) {
        float v = acc[i][j][r] + bv;
        size_t off = (size_t)(rowb + r) * N + col;
        if (C_PACKED) ((uint32_t*)Cv)[off] = pack_split(v);
        else          ((float*)Cv)[off] = v;
      }
    }
  }
}

// ---------- fp32 VALU GEMM (tiny N=48 param GEMM) ----------
__global__ __launch_bounds__(256) void gemm_f32(
    const float* __restrict__ A, int lda,
    const float* __restrict__ W,
    const float* __restrict__ bias,
    float* __restrict__ C, int M, int N, int K) {
  __shared__ float As[16][132];
  __shared__ float Bs[16][128];
  const int tid  = threadIdx.x;
  const int row0 = blockIdx.y * 128;
  const int col0 = blockIdx.x * 128;
  const int ty = tid >> 4;
  const int tx = tid & 15;
  const int a_r = tid >> 2;
  const int a_k = (tid & 3) << 2;
  const int b_r = tid >> 5;
  const int b_c = (tid & 31) << 2;

  float acc[8][8];
#pragma unroll
  for (int i = 0; i < 8; i++)
#pragma unroll
    for (int j = 0; j < 8; j++) acc[i][j] = 0.f;

  float4 areg[2], breg[2];
  const int gc = col0 + b_c;
#pragma unroll
  for (int i = 0; i < 2; i++)
    areg[i] = *(const float4*)(A + (size_t)(row0 + a_r + i * 64) * lda + a_k);
#pragma unroll
  for (int i = 0; i < 2; i++) {
    breg[i] = make_float4(0.f, 0.f, 0.f, 0.f);
    if (gc < N) breg[i] = *(const float4*)(W + (size_t)(b_r + i * 8) * N + gc);
  }

  for (int k0 = 0; k0 < K; k0 += 16) {
#pragma unroll
    for (int i = 0; i < 2; i++) {
      int r = a_r + i * 64;
      As[a_k + 0][r] = areg[i].x;
      As[a_k + 1][r] = areg[i].y;
      As[a_k + 2][r] = areg[i].z;
      As[a_k + 3][r] = areg[i].w;
    }
#pragma unroll
    for (int i = 0; i < 2; i++) *(float4*)(&Bs[b_r + i * 8][b_c]) = breg[i];
    __syncthreads();

    if (k0 + 16 < K) {
#pragma unroll
      for (int i = 0; i < 2; i++)
        areg[i] = *(const float4*)(A + (size_t)(row0 + a_r + i * 64) * lda + (k0 + 16 + a_k));
#pragma unroll
      for (int i = 0; i < 2; i++) {
        breg[i] = make_float4(0.f, 0.f, 0.f, 0.f);
        if (gc < N) breg[i] = *(const float4*)(W + (size_t)(k0 + 16 + b_r + i * 8) * N + gc);
      }
    }

#pragma unroll
    for (int kk = 0; kk < 16; kk++) {
      float af[8], bf[8];
      *(float4*)&af[0] = *(const float4*)&As[kk][ty * 8];
      *(float4*)&af[4] = *(const float4*)&As[kk][ty * 8 + 4];
      *(float4*)&bf[0] = *(const float4*)&Bs[kk][tx * 8];
      *(float4*)&bf[4] = *(const float4*)&Bs[kk][tx * 8 + 4];
#pragma unroll
      for (int i = 0; i < 8; i++)
#pragma unroll
        for (int j = 0; j < 8; j++) acc[i][j] += af[i] * bf[j];
    }
    __syncthreads();
  }
#pragma unroll
  for (int i = 0; i < 8; i++) {
    int r = row0 + ty * 8 + i;
#pragma unroll
    for (int j0 = 0; j0 < 8; j0 += 4) {
      int cc = col0 + tx * 8 + j0;
      if (cc < N) {
        float4 ov;
        ov.x = acc[i][j0 + 0] + bias[cc + 0];
        ov.y = acc[i][j0 + 1] + bias[cc + 1];
        ov.z = acc[i][j0 + 2] + bias[cc + 2];
        ov.w = acc[i][j0 + 3] + bias[cc + 3];
        *(float4*)(C + (size_t)r * N + cc) = ov;
      }
    }
  }
}

// Titans recurrence (r4 scan structure — best measured: 563 µs). One block per (b,h),
// 512 threads = 8 waves x 8 S-rows. q/k L2-normalization FUSED into staging (lanes of a
// wave hold one row's 64 elements -> one DPP wave_sum each); q/k/v packed u32 in qkv;
// LN(o) written packed into the v-slot. 3-barrier pipelined chunk loop.
__global__ __launch_bounds__(512) void titans_rec(
    uint32_t* __restrict__ qkv, const float* __restrict__ p,
    const float* __restrict__ w, const float* __restrict__ bparm) {
  const int bh = blockIdx.x;
  const int b = bh >> 4;
  const int h = bh & 15;
  const int tid = threadIdx.x;
  const int wv = tid >> 6;   // 0..7
  const int l = tid & 63;

  __shared__ float k_s[2][CSZ][DD];
  __shared__ float q_s[2][CSZ][DD];
  __shared__ float v_s[CSZ][DD];
  __shared__ float dkh_s[CSZ][DD];
  __shared__ float part[2][WVS][CSZ][DD];
  __shared__ float4 prm_s[2][CSZ];

  float S[8], M[8];
#pragma unroll
  for (int r = 0; r < 8; r++) { S[r] = 0.f; M[r] = 0.f; }

  const float w_l = w[h * DD + l];
  const float b_l = bparm[h * DD + l];

  uint32_t* qbase = qkv + (size_t)(b * TT) * 3072 + h * DD;
  const float* pbase = p + (size_t)(b * TT) * 48 + h * 3;

  uint32_t rq[2], rk[2], rv[2];
  float rp0 = 0.f, rp1 = 0.f, rp2 = 0.f;
  // ---- prologue: load + commit chunk 0 (with q/k normalize); load chunk 1 into regs ----
  {
#pragma unroll
    for (int i = 0; i < 2; i++) {
      const int row = wv + i * 8;
      size_t roff = (size_t)row * 3072 + l;
      float qv = unpack_f(qbase[roff]);
      float kv = unpack_f(qbase[roff + 1024]);
      float vv = unpack_f(qbase[roff + 2048]);
      float qss = wave_sum(qv * qv);
      float kss = wave_sum(kv * kv);
      q_s[0][row][l] = qv * (1.f / fmaxf(sqrtf(qss), 1e-12f));
      k_s[0][row][l] = kv * (1.f / fmaxf(sqrtf(kss), 1e-12f));
      v_s[row][l] = vv;
    }
    if (tid < CSZ) {
      const float* pp = pbase + (size_t)tid * 48;
      prm_s[0][tid] = make_float4(sigmoidf_(pp[0]), sigmoidf_(pp[1]), sigmoidf_(pp[2]), 0.f);
    }
#pragma unroll
    for (int i = 0; i < 2; i++) {
      size_t roff = (size_t)(CSZ + wv + i * 8) * 3072 + l;
      rq[i] = qbase[roff];
      rk[i] = qbase[roff + 1024];
      rv[i] = qbase[roff + 2048];
    }
    if (tid < CSZ) {
      const float* pp = pbase + (size_t)(CSZ + tid) * 48;
      rp0 = pp[0]; rp1 = pp[1]; rp2 = pp[2];
    }
  }
  __syncthreads();

  for (int nt = 0; nt < NTC; nt++) {
    const int buf = nt & 1;
    float (*partw)[CSZ][DD] = part[buf];       // this chunk's kh, then po
    float (*partr)[CSZ][DD] = part[buf ^ 1];   // previous chunk's po

    // ---- phase A: deferred o/LN/store of chunk nt-1, then kh partials ----
    if (nt > 0) {
#pragma unroll
      for (int i = 0; i < 2; i++) {
        const int t = wv + i * 8;
        float o = 0.f;
#pragma unroll
        for (int ww = 0; ww < WVS; ww++) o += partr[ww][t][l];
        float mu = wave_sum(o) * (1.f / 64.f);
        float xc = o - mu;
        float var = wave_sum(xc * xc) * (1.f / 64.f);
        float rstd = rsqrtf(var + EPSF);
        float y = xc * rstd * w_l + b_l;
        qbase[(size_t)((nt - 1) * CSZ + t) * 3072 + 2048 + l] = pack_split(y);
      }
    }
#pragma unroll
    for (int c = 0; c < CSZ; c++) {
      const float* kp = &k_s[buf][c][wv * 8];
      float4 ka = *(const float4*)kp;          // broadcast reads
      float4 kb = *(const float4*)(kp + 4);
      partw[wv][c][l] = ka.x * S[0] + ka.y * S[1] + ka.z * S[2] + ka.w * S[3]
                      + kb.x * S[4] + kb.y * S[5] + kb.z * S[6] + kb.w * S[7];
    }
    __syncthreads();

    // ---- phase B: LN fwd + bwd — two token rows per wave ----
#pragma unroll
    for (int i = 0; i < 2; i++) {
      const int c = wv + i * 8;
      float kh = 0.f;
#pragma unroll
      for (int ww = 0; ww < WVS; ww++) kh += partw[ww][c][l];
      float mu = wave_sum(kh) * (1.f / 64.f);
      float xc = kh - mu;
      float var = wave_sum(xc * xc) * (1.f / 64.f);
      float rstd = rsqrtf(var + EPSF);
      float xhat = xc * rstd;
      float y = xhat * w_l + b_l;
      float dy = 2.f * (y - v_s[c][l]);
      float wdy = dy * w_l;
      float c1 = wave_sum(xhat * wdy) * (1.f / 64.f);
      float c2 = wave_sum(wdy) * (1.f / 64.f);
      dkh_s[c][l] = (wdy - xhat * c1 - c2) * rstd;
    }
    __syncthreads();

    // ---- phase C: commit next tiles (q/k normalized), issue prefetch, token scan ----
    if (nt + 1 < NTC) {
#pragma unroll
      for (int i = 0; i < 2; i++) {
        const int row = wv + i * 8;
        float qv = unpack_f(rq[i]);
        float kv = unpack_f(rk[i]);
        float qss = wave_sum(qv * qv);
        float kss = wave_sum(kv * kv);
        q_s[buf ^ 1][row][l] = qv * (1.f / fmaxf(sqrtf(qss), 1e-12f));
        k_s[buf ^ 1][row][l] = kv * (1.f / fmaxf(sqrtf(kss), 1e-12f));
        v_s[row][l] = unpack_f(rv[i]);
      }
      if (tid < CSZ)
        prm_s[buf ^ 1][tid] = make_float4(sigmoidf_(rp0), sigmoidf_(rp1), sigmoidf_(rp2), 0.f);
    }
    if (nt + 2 < NTC) {
#pragma unroll
      for (int i = 0; i < 2; i++) {
        size_t roff = (size_t)((nt + 2) * CSZ + wv + i * 8) * 3072 + l;
        rq[i] = qbase[roff];
        rk[i] = qbase[roff + 1024];
        rv[i] = qbase[roff + 2048];
      }
      if (tid < CSZ) {
        const float* pp = pbase + (size_t)((nt + 2) * CSZ + tid) * 48;
        rp0 = pp[0]; rp1 = pp[1]; rp2 = pp[2];
      }
    }
#pragma unroll
    for (int t = 0; t < CSZ; t++) {
      float4 prm = prm_s[buf][t];
      float a = prm.x * dkh_s[t][l];
      float et = prm.z;
      float bet = 1.f - prm.y;
      const float* kp = &k_s[buf][t][wv * 8];
      const float* qp = &q_s[buf][t][wv * 8];
      float4 ka = *(const float4*)kp, kb = *(const float4*)(kp + 4);
      float4 qa = *(const float4*)qp, qb = *(const float4*)(qp + 4);
      float po;
      M[0] = et * M[0] - a * ka.x;  S[0] = bet * S[0] + M[0];  po  = qa.x * S[0];
      M[1] = et * M[1] - a * ka.y;  S[1] = bet * S[1] + M[1];  po += qa.y * S[1];
      M[2] = et * M[2] - a * ka.z;  S[2] = bet * S[2] + M[2];  po += qa.z * S[2];
      M[3] = et * M[3] - a * ka.w;  S[3] = bet * S[3] + M[3];  po += qa.w * S[3];
      M[4] = et * M[4] - a * kb.x;  S[4] = bet * S[4] + M[4];  po += qb.x * S[4];
      M[5] = et * M[5] - a * kb.y;  S[5] = bet * S[5] + M[5];  po += qb.y * S[5];
      M[6] = et * M[6] - a * kb.z;  S[6] = bet * S[6] + M[6];  po += qb.z * S[6];
      M[7] = et * M[7] - a * kb.w;  S[7] = bet * S[7] + M[7];  po += qb.w * S[7];
      partw[wv][t][l] = po;
    }
    __syncthreads();
  }

  // ---- epilogue: deferred D for the last chunk ----
  {
    float (*partr)[CSZ][DD] = part[(NTC - 1) & 1];
#pragma unroll
    for (int i = 0; i < 2; i++) {
      const int t = wv + i * 8;
      float o = 0.f;
#pragma unroll
      for (int ww = 0; ww < WVS; ww++) o += partr[ww][t][l];
      float mu = wave_sum(o) * (1.f / 64.f);
      float xc = o - mu;
      float var = wave_sum(xc * xc) * (1.f / 64.f);
      float rstd = rsqrtf(var + EPSF);
      float y = xc * rstd * w_l + b_l;
      qbase[(size_t)((NTC - 1) * CSZ + t) * 3072 + 2048 + l] = pack_split(y);
    }
  }
}

extern "C" void kernel_launch(void* const* d_in, const int* in_sizes, int n_in,
                              void* d_out, int out_size, void* d_ws, size_t ws_size,
                              hipStream_t stream) {
  const float* x      = (const float*)d_in[0];
  const float* W_attn = (const float*)d_in[1];
  const float* b_attn = (const float*)d_in[2];
  const float* W_parm = (const float*)d_in[3];
  const float* b_parm = (const float*)d_in[4];
  const float* W_proj = (const float*)d_in[5];
  const float* b_proj = (const float*)d_in[6];
  const float* w      = (const float*)d_in[7];
  const float* bb     = (const float*)d_in[8];
  float* out = (float*)d_out;

  const int M = BB * TT;        // 8192
  float* qkv = (float*)d_ws;                               // M x 3072 (packed u32 after GEMM)
  float* pbf = qkv + (size_t)M * 3072;                     // M x 48 f32
  unsigned short* wattn_hi = (unsigned short*)(pbf + (size_t)M * 48);   // 3072 x 1024
  unsigned short* wattn_lo = wattn_hi + (size_t)3072 * 1024;
  unsigned short* wproj_hi = wattn_lo + (size_t)3072 * 1024;            // 1024 x 1024
  unsigned short* wproj_lo = wproj_hi + (size_t)1024 * 1024;

  // pre-split + transpose weights into hi/lo planes (one-time, memory-bound)
  split_transpose_pl<<<dim3(3072 / 32, 1024 / 32), 256, 0, stream>>>(W_attn, wattn_hi, wattn_lo, 1024, 3072);
  split_transpose_pl<<<dim3(1024 / 32, 1024 / 32), 256, 0, stream>>>(W_proj, wproj_hi, wproj_lo, 1024, 1024);

  // qkv = x @ W_attn + b_attn  (A f32 split on the fly; B planes; C packed)
  gemm_planes<2, true><<<dim3(3072 / 128, M / 128), 256, 0, stream>>>(
      x, CCH, wattn_hi, wattn_lo, b_attn, qkv, M, 3072, CCH);
  // p = x @ W_param + b_param (fp32 VALU; sigmoid applied at use)
  gemm_f32<<<dim3(1, M / 128), 256, 0, stream>>>(x, CCH, W_parm, b_parm, pbf, M, 48, CCH);
  // recurrence (q/k normalize fused); writes packed LN(o) into v-slot
  titans_rec<<<BB * HH, 512, 0, stream>>>((uint32_t*)qkv, pbf, w, bb);
  // out = o @ W_proj + b_proj  (A packed from v-slot; B planes; C f32)
  gemm_planes<1, false><<<dim3(CCH / 128, M / 128), 256, 0, stream>>>(
      (uint32_t*)qkv + 2048, 3072, wproj_hi, wproj_lo, b_proj, out, M, CCH, CCH);
}

// Round 7
// 1022.645 us; speedup vs baseline: 1.2106x; 1.2106x over previous
//
#include <hip/hip_runtime.h>
#include <cstddef>
#include <cstdint>
#include <math.h>

#define BB   4
#define TT   2048
#define CCH  1024
#define HH   16
#define DD   64
#define CSZ  16
#define NTC  128
#define EPSF 1e-5f
#define WVS  8

typedef __attribute__((ext_vector_type(8))) short bf16x8;
typedef __attribute__((ext_vector_type(4))) float f32x4;
typedef __attribute__((ext_vector_type(2))) float f32x2;

// ---------- split-float helpers: f32 ≈ hi(bf16) + lo(bf16), packed (hi | lo<<16) ----------
__device__ __forceinline__ uint32_t pack_split(float f) {
  uint32_t b = __float_as_uint(f);
  uint32_t uh = (b + 0x7fffu + ((b >> 16) & 1u)) >> 16;   // RNE bf16 of f
  float fh = __uint_as_float(uh << 16);
  float r = f - fh;
  return uh | (__float_as_uint(r) & 0xffff0000u);          // lo = trunc bf16 of residual
}
__device__ __forceinline__ float unpack_f(uint32_t u) {
  return __uint_as_float(u << 16) + __uint_as_float(u & 0xffff0000u);
}

// Wave64 sum via DPP (VALU pipe, not LDS pipe).
__device__ __forceinline__ float wave_sum(float x) {
  float v = x;
  v += __int_as_float(__builtin_amdgcn_update_dpp(0, __float_as_int(v), 0x111, 0xf, 0xf, true));
  v += __int_as_float(__builtin_amdgcn_update_dpp(0, __float_as_int(v), 0x112, 0xf, 0xf, true));
  v += __int_as_float(__builtin_amdgcn_update_dpp(0, __float_as_int(v), 0x114, 0xf, 0xf, true));
  v += __int_as_float(__builtin_amdgcn_update_dpp(0, __float_as_int(v), 0x118, 0xf, 0xf, true));
  v += __int_as_float(__builtin_amdgcn_update_dpp(0, __float_as_int(v), 0x142, 0xa, 0xf, true));
  v += __int_as_float(__builtin_amdgcn_update_dpp(0, __float_as_int(v), 0x143, 0xc, 0xf, true));
  return __int_as_float(__builtin_amdgcn_readlane(__float_as_int(v), 63));
}

__device__ __forceinline__ float sigmoidf_(float x) {
  return 1.f / (1.f + expf(-x));
}

// ---------- transpose + split: W (KxN f32) -> Wt (NxK packed u32) ----------
__global__ __launch_bounds__(256) void split_transpose(
    const float* __restrict__ W, uint32_t* __restrict__ Wt, int K, int N) {
  __shared__ float t[32][33];
  const int n0 = blockIdx.x * 32, k0 = blockIdx.y * 32;
  const int tx = threadIdx.x & 31, ty = threadIdx.x >> 5;  // ty 0..7
#pragma unroll
  for (int i = 0; i < 4; i++)
    t[ty + i * 8][tx] = W[(size_t)(k0 + ty + i * 8) * N + n0 + tx];
  __syncthreads();
#pragma unroll
  for (int i = 0; i < 4; i++)
    Wt[(size_t)(n0 + ty + i * 8) * K + k0 + tx] = pack_split(t[tx][ty + i * 8]);
}

// ---------- split-bf16 MFMA GEMM: C = A @ Bt^T + bias (r4-proven version) ----------
template<bool A_PACKED, bool C_PACKED>
__global__ __launch_bounds__(256) void gemm_split(
    const void* __restrict__ Av, int lda,
    const uint32_t* __restrict__ Bt,
    const float* __restrict__ bias,
    void* __restrict__ Cv, int M, int N, int K) {
  __shared__ unsigned short Ahi[128][40];
  __shared__ unsigned short Alo[128][40];
  __shared__ unsigned short Bhi[128][40];
  __shared__ unsigned short Blo[128][40];

  const int tid = threadIdx.x;
  const int row0 = blockIdx.y * 128;
  const int col0 = blockIdx.x * 128;
  const int wv = tid >> 6;
  const int l  = tid & 63;
  const int wr = wv >> 1, wc = wv & 1;
  const int lrow = l & 15;
  const int kgrp = (l >> 4) * 8;

  const int sr = tid >> 1;
  const int sk = (tid & 1) * 16;

  f32x4 acc[4][4];
#pragma unroll
  for (int i = 0; i < 4; i++)
#pragma unroll
    for (int j = 0; j < 4; j++) acc[i][j] = (f32x4){0.f, 0.f, 0.f, 0.f};

  for (int k0 = 0; k0 < K; k0 += 32) {
    {
      uint32_t hp[8], lp[8];
      if (A_PACKED) {
        const uint32_t* Ap = (const uint32_t*)Av + (size_t)(row0 + sr) * lda + k0 + sk;
        uint32_t u[16];
#pragma unroll
        for (int i = 0; i < 4; i++) *(uint4*)&u[i * 4] = *(const uint4*)(Ap + i * 4);
#pragma unroll
        for (int j = 0; j < 8; j++) {
          hp[j] = (u[2 * j] & 0xffffu) | (u[2 * j + 1] << 16);
          lp[j] = (u[2 * j] >> 16) | (u[2 * j + 1] & 0xffff0000u);
        }
      } else {
        const float* Ap = (const float*)Av + (size_t)(row0 + sr) * lda + k0 + sk;
        float f[16];
#pragma unroll
        for (int i = 0; i < 4; i++) *(float4*)&f[i * 4] = *(const float4*)(Ap + i * 4);
        uint32_t uh[16], ulr[16];
#pragma unroll
        for (int j = 0; j < 16; j++) {
          uint32_t b = __float_as_uint(f[j]);
          uint32_t h = (b + 0x7fffu + ((b >> 16) & 1u)) >> 16;
          uh[j] = h;
          ulr[j] = __float_as_uint(f[j] - __uint_as_float(h << 16));
        }
#pragma unroll
        for (int j = 0; j < 8; j++) {
          hp[j] = uh[2 * j] | (uh[2 * j + 1] << 16);
          lp[j] = (ulr[2 * j] >> 16) | (ulr[2 * j + 1] & 0xffff0000u);
        }
      }
      *(uint4*)&Ahi[sr][sk]     = *(uint4*)&hp[0];
      *(uint4*)&Ahi[sr][sk + 8] = *(uint4*)&hp[4];
      *(uint4*)&Alo[sr][sk]     = *(uint4*)&lp[0];
      *(uint4*)&Alo[sr][sk + 8] = *(uint4*)&lp[4];
    }
    {
      const uint32_t* Bp = Bt + (size_t)(col0 + sr) * K + k0 + sk;
      uint32_t u[16], hp[8], lp[8];
#pragma unroll
      for (int i = 0; i < 4; i++) *(uint4*)&u[i * 4] = *(const uint4*)(Bp + i * 4);
#pragma unroll
      for (int j = 0; j < 8; j++) {
        hp[j] = (u[2 * j] & 0xffffu) | (u[2 * j + 1] << 16);
        lp[j] = (u[2 * j] >> 16) | (u[2 * j + 1] & 0xffff0000u);
      }
      *(uint4*)&Bhi[sr][sk]     = *(uint4*)&hp[0];
      *(uint4*)&Bhi[sr][sk + 8] = *(uint4*)&hp[4];
      *(uint4*)&Blo[sr][sk]     = *(uint4*)&lp[0];
      *(uint4*)&Blo[sr][sk + 8] = *(uint4*)&lp[4];
    }
    __syncthreads();

    bf16x8 bh[4], bl[4];
#pragma unroll
    for (int j = 0; j < 4; j++) {
      bh[j] = *(const bf16x8*)&Bhi[wc * 64 + j * 16 + lrow][kgrp];
      bl[j] = *(const bf16x8*)&Blo[wc * 64 + j * 16 + lrow][kgrp];
    }
#pragma unroll
    for (int i = 0; i < 4; i++) {
      bf16x8 ah = *(const bf16x8*)&Ahi[wr * 64 + i * 16 + lrow][kgrp];
      bf16x8 al = *(const bf16x8*)&Alo[wr * 64 + i * 16 + lrow][kgrp];
#pragma unroll
      for (int j = 0; j < 4; j++) {
        acc[i][j] = __builtin_amdgcn_mfma_f32_16x16x32_bf16(ah, bh[j], acc[i][j], 0, 0, 0);
        acc[i][j] = __builtin_amdgcn_mfma_f32_16x16x32_bf16(ah, bl[j], acc[i][j], 0, 0, 0);
        acc[i][j] = __builtin_amdgcn_mfma_f32_16x16x32_bf16(al, bh[j], acc[i][j], 0, 0, 0);
      }
    }
    __syncthreads();
  }

  const int crow4 = (l >> 4) * 4;
#pragma unroll
  for (int i = 0; i < 4; i++) {
#pragma unroll
    for (int j = 0; j < 4; j++) {
      const int col = col0 + wc * 64 + j * 16 + lrow;
      const float bv = bias[col];
      const int rowb = row0 + wr * 64 + i * 16 + crow4;
#pragma unroll
      for (int r = 0; r < 4; r++) {
        float v = acc[i][j][r] + bv;
        size_t off = (size_t)(rowb + r) * N + col;
        if (C_PACKED) ((uint32_t*)Cv)[off] = pack_split(v);
        else          ((float*)Cv)[off] = v;
      }
    }
  }
}

// ---------- fp32 VALU GEMM (tiny N=48 param GEMM) ----------
__global__ __launch_bounds__(256) void gemm_f32(
    const float* __restrict__ A, int lda,
    const float* __restrict__ W,
    const float* __restrict__ bias,
    float* __restrict__ C, int M, int N, int K) {
  __shared__ float As[16][132];
  __shared__ float Bs[16][128];
  const int tid  = threadIdx.x;
  const int row0 = blockIdx.y * 128;
  const int col0 = blockIdx.x * 128;
  const int ty = tid >> 4;
  const int tx = tid & 15;
  const int a_r = tid >> 2;
  const int a_k = (tid & 3) << 2;
  const int b_r = tid >> 5;
  const int b_c = (tid & 31) << 2;

  float acc[8][8];
#pragma unroll
  for (int i = 0; i < 8; i++)
#pragma unroll
    for (int j = 0; j < 8; j++) acc[i][j] = 0.f;

  float4 areg[2], breg[2];
  const int gc = col0 + b_c;
#pragma unroll
  for (int i = 0; i < 2; i++)
    areg[i] = *(const float4*)(A + (size_t)(row0 + a_r + i * 64) * lda + a_k);
#pragma unroll
  for (int i = 0; i < 2; i++) {
    breg[i] = make_float4(0.f, 0.f, 0.f, 0.f);
    if (gc < N) breg[i] = *(const float4*)(W + (size_t)(b_r + i * 8) * N + gc);
  }

  for (int k0 = 0; k0 < K; k0 += 16) {
#pragma unroll
    for (int i = 0; i < 2; i++) {
      int r = a_r + i * 64;
      As[a_k + 0][r] = areg[i].x;
      As[a_k + 1][r] = areg[i].y;
      As[a_k + 2][r] = areg[i].z;
      As[a_k + 3][r] = areg[i].w;
    }
#pragma unroll
    for (int i = 0; i < 2; i++) *(float4*)(&Bs[b_r + i * 8][b_c]) = breg[i];
    __syncthreads();

    if (k0 + 16 < K) {
#pragma unroll
      for (int i = 0; i < 2; i++)
        areg[i] = *(const float4*)(A + (size_t)(row0 + a_r + i * 64) * lda + (k0 + 16 + a_k));
#pragma unroll
      for (int i = 0; i < 2; i++) {
        breg[i] = make_float4(0.f, 0.f, 0.f, 0.f);
        if (gc < N) breg[i] = *(const float4*)(W + (size_t)(k0 + 16 + b_r + i * 8) * N + gc);
      }
    }

#pragma unroll
    for (int kk = 0; kk < 16; kk++) {
      float af[8], bf[8];
      *(float4*)&af[0] = *(const float4*)&As[kk][ty * 8];
      *(float4*)&af[4] = *(const float4*)&As[kk][ty * 8 + 4];
      *(float4*)&bf[0] = *(const float4*)&Bs[kk][tx * 8];
      *(float4*)&bf[4] = *(const float4*)&Bs[kk][tx * 8 + 4];
#pragma unroll
      for (int i = 0; i < 8; i++)
#pragma unroll
        for (int j = 0; j < 8; j++) acc[i][j] += af[i] * bf[j];
    }
    __syncthreads();
  }
#pragma unroll
  for (int i = 0; i < 8; i++) {
    int r = row0 + ty * 8 + i;
#pragma unroll
    for (int j0 = 0; j0 < 8; j0 += 4) {
      int cc = col0 + tx * 8 + j0;
      if (cc < N) {
        float4 ov;
        ov.x = acc[i][j0 + 0] + bias[cc + 0];
        ov.y = acc[i][j0 + 1] + bias[cc + 1];
        ov.z = acc[i][j0 + 2] + bias[cc + 2];
        ov.w = acc[i][j0 + 3] + bias[cc + 3];
        *(float4*)(C + (size_t)r * N + cc) = ov;
      }
    }
  }
}

// L2-normalize packed q/k rows (length 64) in-place. One wave per row.
__global__ __launch_bounds__(256) void normalize_qk(uint32_t* __restrict__ qkv) {
  const int idx = blockIdx.x * 4 + (threadIdx.x >> 6);
  const int l = threadIdx.x & 63;
  const int rowBT = idx >> 5;
  const int rem = idx & 31;
  const int which = rem >> 4;
  const int h = rem & 15;
  const size_t addr = (size_t)rowBT * 3072 + (size_t)which * 1024 + h * 64 + l;
  float v = unpack_f(qkv[addr]);
  float ss = wave_sum(v * v);
  float sc = 1.f / fmaxf(sqrtf(ss), 1e-12f);
  qkv[addr] = pack_split(v * sc);
}

// Titans recurrence (r4 structure — best measured 563 µs) with PACKED-fp32 hot loops:
// S/M state held as 4 f32x2 pairs; phase-A kh partials and phase-C token scan use
// 2-wide vector math -> v_pk_fma_f32/v_pk_mul_f32 (halves VALU issue count of the
// dominant scan). One block per (b,h), 512 threads = 8 waves x 8 S-rows.
__global__ __launch_bounds__(512) void titans_rec(
    uint32_t* __restrict__ qkv, const float* __restrict__ p,
    const float* __restrict__ w, const float* __restrict__ bparm) {
  const int bh = blockIdx.x;
  const int b = bh >> 4;
  const int h = bh & 15;
  const int tid = threadIdx.x;
  const int wv = tid >> 6;   // 0..7
  const int l = tid & 63;

  __shared__ float k_s[2][CSZ][DD];
  __shared__ float q_s[2][CSZ][DD];
  __shared__ float v_s[CSZ][DD];
  __shared__ float dkh_s[CSZ][DD];
  __shared__ float part[2][WVS][CSZ][DD];
  __shared__ float4 prm_s[2][CSZ];

  f32x2 S2[4], M2[4];
#pragma unroll
  for (int r = 0; r < 4; r++) { S2[r] = (f32x2){0.f, 0.f}; M2[r] = (f32x2){0.f, 0.f}; }

  const float w_l = w[h * DD + l];
  const float b_l = bparm[h * DD + l];

  uint32_t* qbase = qkv + (size_t)(b * TT) * 3072 + h * DD;
  const float* pbase = p + (size_t)(b * TT) * 48 + h * 3;

  uint32_t rq[2], rk[2], rv[2];
  float rp0 = 0.f, rp1 = 0.f, rp2 = 0.f;
  // ---- prologue: load + commit chunk 0; load chunk 1 into regs ----
  {
#pragma unroll
    for (int i = 0; i < 2; i++) {
      const int row = wv + i * 8;
      size_t roff = (size_t)row * 3072 + l;
      q_s[0][row][l] = unpack_f(qbase[roff]);
      k_s[0][row][l] = unpack_f(qbase[roff + 1024]);
      v_s[row][l]    = unpack_f(qbase[roff + 2048]);
    }
    if (tid < CSZ) {
      const float* pp = pbase + (size_t)tid * 48;
      prm_s[0][tid] = make_float4(sigmoidf_(pp[0]), sigmoidf_(pp[1]), sigmoidf_(pp[2]), 0.f);
    }
#pragma unroll
    for (int i = 0; i < 2; i++) {
      size_t roff = (size_t)(CSZ + wv + i * 8) * 3072 + l;
      rq[i] = qbase[roff];
      rk[i] = qbase[roff + 1024];
      rv[i] = qbase[roff + 2048];
    }
    if (tid < CSZ) {
      const float* pp = pbase + (size_t)(CSZ + tid) * 48;
      rp0 = pp[0]; rp1 = pp[1]; rp2 = pp[2];
    }
  }
  __syncthreads();

  for (int nt = 0; nt < NTC; nt++) {
    const int buf = nt & 1;
    float (*partw)[CSZ][DD] = part[buf];       // this chunk's kh, then po
    float (*partr)[CSZ][DD] = part[buf ^ 1];   // previous chunk's po

    // ---- phase A: deferred o/LN/store of chunk nt-1, then kh partials (packed) ----
    if (nt > 0) {
#pragma unroll
      for (int i = 0; i < 2; i++) {
        const int t = wv + i * 8;
        float o = 0.f;
#pragma unroll
        for (int ww = 0; ww < WVS; ww++) o += partr[ww][t][l];
        float mu = wave_sum(o) * (1.f / 64.f);
        float xc = o - mu;
        float var = wave_sum(xc * xc) * (1.f / 64.f);
        float rstd = rsqrtf(var + EPSF);
        float y = xc * rstd * w_l + b_l;
        qbase[(size_t)((nt - 1) * CSZ + t) * 3072 + 2048 + l] = pack_split(y);
      }
    }
#pragma unroll
    for (int c = 0; c < CSZ; c++) {
      const f32x2* kp2 = (const f32x2*)&k_s[buf][c][wv * 8];
      f32x2 a2;
      a2 = kp2[0] * S2[0];
      a2 = kp2[1] * S2[1] + a2;
      a2 = kp2[2] * S2[2] + a2;
      a2 = kp2[3] * S2[3] + a2;
      partw[wv][c][l] = a2.x + a2.y;
    }
    __syncthreads();

    // ---- phase B: LN fwd + bwd — two token rows per wave ----
#pragma unroll
    for (int i = 0; i < 2; i++) {
      const int c = wv + i * 8;
      float kh = 0.f;
#pragma unroll
      for (int ww = 0; ww < WVS; ww++) kh += partw[ww][c][l];
      float mu = wave_sum(kh) * (1.f / 64.f);
      float xc = kh - mu;
      float var = wave_sum(xc * xc) * (1.f / 64.f);
      float rstd = rsqrtf(var + EPSF);
      float xhat = xc * rstd;
      float y = xhat * w_l + b_l;
      float dy = 2.f * (y - v_s[c][l]);
      float wdy = dy * w_l;
      float c1 = wave_sum(xhat * wdy) * (1.f / 64.f);
      float c2 = wave_sum(wdy) * (1.f / 64.f);
      dkh_s[c][l] = (wdy - xhat * c1 - c2) * rstd;
    }
    __syncthreads();

    // ---- phase C: commit next tiles, issue prefetch, token scan (packed) ----
    if (nt + 1 < NTC) {
#pragma unroll
      for (int i = 0; i < 2; i++) {
        const int row = wv + i * 8;
        k_s[buf ^ 1][row][l] = unpack_f(rk[i]);
        q_s[buf ^ 1][row][l] = unpack_f(rq[i]);
        v_s[row][l] = unpack_f(rv[i]);
      }
      if (tid < CSZ)
        prm_s[buf ^ 1][tid] = make_float4(sigmoidf_(rp0), sigmoidf_(rp1), sigmoidf_(rp2), 0.f);
    }
    if (nt + 2 < NTC) {
#pragma unroll
      for (int i = 0; i < 2; i++) {
        size_t roff = (size_t)((nt + 2) * CSZ + wv + i * 8) * 3072 + l;
        rq[i] = qbase[roff];
        rk[i] = qbase[roff + 1024];
        rv[i] = qbase[roff + 2048];
      }
      if (tid < CSZ) {
        const float* pp = pbase + (size_t)((nt + 2) * CSZ + tid) * 48;
        rp0 = pp[0]; rp1 = pp[1]; rp2 = pp[2];
      }
    }
#pragma unroll
    for (int t = 0; t < CSZ; t++) {
      float4 prm = prm_s[buf][t];
      float a = prm.x * dkh_s[t][l];
      const f32x2 na2 = (f32x2){-a, -a};
      const f32x2 et2 = (f32x2){prm.z, prm.z};
      const f32x2 be2 = (f32x2){1.f - prm.y, 1.f - prm.y};
      const f32x2* kp2 = (const f32x2*)&k_s[buf][t][wv * 8];
      const f32x2* qp2 = (const f32x2*)&q_s[buf][t][wv * 8];
      f32x2 po2 = (f32x2){0.f, 0.f};
#pragma unroll
      for (int pq = 0; pq < 4; pq++) {
        M2[pq] = et2 * M2[pq] + na2 * kp2[pq];   // pk_mul + pk_fma
        S2[pq] = be2 * S2[pq] + M2[pq];          // pk_fma
        po2    = qp2[pq] * S2[pq] + po2;         // pk_fma
      }
      partw[wv][t][l] = po2.x + po2.y;
    }
    __syncthreads();
  }

  // ---- epilogue: deferred D for the last chunk ----
  {
    float (*partr)[CSZ][DD] = part[(NTC - 1) & 1];
#pragma unroll
    for (int i = 0; i < 2; i++) {
      const int t = wv + i * 8;
      float o = 0.f;
#pragma unroll
      for (int ww = 0; ww < WVS; ww++) o += partr[ww][t][l];
      float mu = wave_sum(o) * (1.f / 64.f);
      float xc = o - mu;
      float var = wave_sum(xc * xc) * (1.f / 64.f);
      float rstd = rsqrtf(var + EPSF);
      float y = xc * rstd * w_l + b_l;
      qbase[(size_t)((NTC - 1) * CSZ + t) * 3072 + 2048 + l] = pack_split(y);
    }
  }
}

extern "C" void kernel_launch(void* const* d_in, const int* in_sizes, int n_in,
                              void* d_out, int out_size, void* d_ws, size_t ws_size,
                              hipStream_t stream) {
  const float* x      = (const float*)d_in[0];
  const float* W_attn = (const float*)d_in[1];
  const float* b_attn = (const float*)d_in[2];
  const float* W_parm = (const float*)d_in[3];
  const float* b_parm = (const float*)d_in[4];
  const float* W_proj = (const float*)d_in[5];
  const float* b_proj = (const float*)d_in[6];
  const float* w      = (const float*)d_in[7];
  const float* bb     = (const float*)d_in[8];
  float* out = (float*)d_out;

  const int M = BB * TT;        // 8192
  float* qkv = (float*)d_ws;                               // M x 3072 (packed u32)
  float* pbf = qkv + (size_t)M * 3072;                     // M x 48 f32
  uint32_t* wattn_t = (uint32_t*)(pbf + (size_t)M * 48);   // 3072 x 1024 packed
  uint32_t* wproj_t = wattn_t + (size_t)3072 * 1024;       // 1024 x 1024 packed

  split_transpose<<<dim3(3072 / 32, 1024 / 32), 256, 0, stream>>>(W_attn, wattn_t, 1024, 3072);
  split_transpose<<<dim3(1024 / 32, 1024 / 32), 256, 0, stream>>>(W_proj, wproj_t, 1024, 1024);

  gemm_split<false, true><<<dim3(3072 / 128, M / 128), 256, 0, stream>>>(
      x, CCH, wattn_t, b_attn, qkv, M, 3072, CCH);
  gemm_f32<<<dim3(1, M / 128), 256, 0, stream>>>(x, CCH, W_parm, b_parm, pbf, M, 48, CCH);
  normalize_qk<<<(M * 2 * HH) / 4, 256, 0, stream>>>((uint32_t*)qkv);
  titans_rec<<<BB * HH, 512, 0, stream>>>((uint32_t*)qkv, pbf, w, bb);
  gemm_split<true, false><<<dim3(CCH / 128, M / 128), 256, 0, stream>>>(
      (uint32_t*)qkv + 2048, 3072, wproj_t, b_proj, out, M, CCH, CCH);
}

// Round 8
// 977.430 us; speedup vs baseline: 1.2666x; 1.0463x over previous
//
#include <hip/hip_runtime.h>
#include <cstddef>
#include <cstdint>
#include <math.h>

#define BB   4
#define TT   2048
#define CCH  1024
#define HH   16
#define DD   64
#define CSZ  16
#define NTC  128
#define EPSF 1e-5f
#define WVS  8

typedef __attribute__((ext_vector_type(8))) short bf16x8;
typedef __attribute__((ext_vector_type(4))) float f32x4;
typedef __attribute__((ext_vector_type(2))) float f32x2;

// Barrier that flushes LDS ops only (cross-wave deps here are all LDS).
// Unlike __syncthreads(), does NOT drain vmcnt -> global stores and register
// prefetch loads stay in flight across the barrier (guide T4). Compiler still
// auto-inserts vmcnt(N) before each use of a prefetched register.
__device__ __forceinline__ void bar_lds() {
  asm volatile("s_waitcnt lgkmcnt(0)" ::: "memory");
  __builtin_amdgcn_s_barrier();
}

// ---------- split-float helpers: f32 ≈ hi(bf16) + lo(bf16), packed (hi | lo<<16) ----------
__device__ __forceinline__ uint32_t pack_split(float f) {
  uint32_t b = __float_as_uint(f);
  uint32_t uh = (b + 0x7fffu + ((b >> 16) & 1u)) >> 16;   // RNE bf16 of f
  float fh = __uint_as_float(uh << 16);
  float r = f - fh;
  return uh | (__float_as_uint(r) & 0xffff0000u);          // lo = trunc bf16 of residual
}
__device__ __forceinline__ float unpack_f(uint32_t u) {
  return __uint_as_float(u << 16) + __uint_as_float(u & 0xffff0000u);
}

// Wave64 sum via DPP (VALU pipe, not LDS pipe).
__device__ __forceinline__ float wave_sum(float x) {
  float v = x;
  v += __int_as_float(__builtin_amdgcn_update_dpp(0, __float_as_int(v), 0x111, 0xf, 0xf, true));
  v += __int_as_float(__builtin_amdgcn_update_dpp(0, __float_as_int(v), 0x112, 0xf, 0xf, true));
  v += __int_as_float(__builtin_amdgcn_update_dpp(0, __float_as_int(v), 0x114, 0xf, 0xf, true));
  v += __int_as_float(__builtin_amdgcn_update_dpp(0, __float_as_int(v), 0x118, 0xf, 0xf, true));
  v += __int_as_float(__builtin_amdgcn_update_dpp(0, __float_as_int(v), 0x142, 0xa, 0xf, true));
  v += __int_as_float(__builtin_amdgcn_update_dpp(0, __float_as_int(v), 0x143, 0xc, 0xf, true));
  return __int_as_float(__builtin_amdgcn_readlane(__float_as_int(v), 63));
}

__device__ __forceinline__ float sigmoidf_(float x) {
  return 1.f / (1.f + expf(-x));
}

// ---------- transpose + split: W (KxN f32) -> Wt (NxK packed u32) ----------
__global__ __launch_bounds__(256) void split_transpose(
    const float* __restrict__ W, uint32_t* __restrict__ Wt, int K, int N) {
  __shared__ float t[32][33];
  const int n0 = blockIdx.x * 32, k0 = blockIdx.y * 32;
  const int tx = threadIdx.x & 31, ty = threadIdx.x >> 5;  // ty 0..7
#pragma unroll
  for (int i = 0; i < 4; i++)
    t[ty + i * 8][tx] = W[(size_t)(k0 + ty + i * 8) * N + n0 + tx];
  __syncthreads();
#pragma unroll
  for (int i = 0; i < 4; i++)
    Wt[(size_t)(n0 + ty + i * 8) * K + k0 + tx] = pack_split(t[tx][ty + i * 8]);
}

// ---------- split-bf16 MFMA GEMM: C = A @ Bt^T + bias ----------
// lgkm-only barriers: register-prefetch global loads span the K-loop barriers
// (previously __syncthreads drained vmcnt(0) every tile = full HBM latency on
// the barrier path).
template<bool A_PACKED, bool C_PACKED>
__global__ __launch_bounds__(256) void gemm_split(
    const void* __restrict__ Av, int lda,
    const uint32_t* __restrict__ Bt,
    const float* __restrict__ bias,
    void* __restrict__ Cv, int M, int N, int K) {
  __shared__ unsigned short Ahi[128][40];
  __shared__ unsigned short Alo[128][40];
  __shared__ unsigned short Bhi[128][40];
  __shared__ unsigned short Blo[128][40];

  const int tid = threadIdx.x;
  const int row0 = blockIdx.y * 128;
  const int col0 = blockIdx.x * 128;
  const int wv = tid >> 6;
  const int l  = tid & 63;
  const int wr = wv >> 1, wc = wv & 1;
  const int lrow = l & 15;
  const int kgrp = (l >> 4) * 8;

  const int sr = tid >> 1;
  const int sk = (tid & 1) * 16;

  f32x4 acc[4][4];
#pragma unroll
  for (int i = 0; i < 4; i++)
#pragma unroll
    for (int j = 0; j < 4; j++) acc[i][j] = (f32x4){0.f, 0.f, 0.f, 0.f};

  uint4 pa[4];    // A_PACKED: 16 packed u32
  float4 pf[4];   // !A_PACKED: 16 floats
  uint4 pb[4];    // B: 16 packed u32

  auto load_tile = [&](int k0) {
    if (A_PACKED) {
      const uint32_t* Ap = (const uint32_t*)Av + (size_t)(row0 + sr) * lda + k0 + sk;
#pragma unroll
      for (int i = 0; i < 4; i++) pa[i] = *(const uint4*)(Ap + i * 4);
    } else {
      const float* Ap = (const float*)Av + (size_t)(row0 + sr) * lda + k0 + sk;
#pragma unroll
      for (int i = 0; i < 4; i++) pf[i] = *(const float4*)(Ap + i * 4);
    }
    const uint32_t* Bp = Bt + (size_t)(col0 + sr) * K + k0 + sk;
#pragma unroll
    for (int i = 0; i < 4; i++) pb[i] = *(const uint4*)(Bp + i * 4);
  };

  auto commit_tile = [&]() {
    uint32_t hp[8], lp[8];
    if (A_PACKED) {
      uint32_t u[16];
#pragma unroll
      for (int i = 0; i < 4; i++) *(uint4*)&u[i * 4] = pa[i];
#pragma unroll
      for (int j = 0; j < 8; j++) {
        hp[j] = (u[2 * j] & 0xffffu) | (u[2 * j + 1] << 16);
        lp[j] = (u[2 * j] >> 16) | (u[2 * j + 1] & 0xffff0000u);
      }
    } else {
      float f[16];
#pragma unroll
      for (int i = 0; i < 4; i++) *(float4*)&f[i * 4] = pf[i];
      uint32_t uh[16], ulr[16];
#pragma unroll
      for (int j = 0; j < 16; j++) {
        uint32_t b = __float_as_uint(f[j]);
        uint32_t h = (b + 0x7fffu + ((b >> 16) & 1u)) >> 16;
        uh[j] = h;
        ulr[j] = __float_as_uint(f[j] - __uint_as_float(h << 16));
      }
#pragma unroll
      for (int j = 0; j < 8; j++) {
        hp[j] = uh[2 * j] | (uh[2 * j + 1] << 16);
        lp[j] = (ulr[2 * j] >> 16) | (ulr[2 * j + 1] & 0xffff0000u);
      }
    }
    *(uint4*)&Ahi[sr][sk]     = *(uint4*)&hp[0];
    *(uint4*)&Ahi[sr][sk + 8] = *(uint4*)&hp[4];
    *(uint4*)&Alo[sr][sk]     = *(uint4*)&lp[0];
    *(uint4*)&Alo[sr][sk + 8] = *(uint4*)&lp[4];
    {
      uint32_t u[16], bh[8], bl[8];
#pragma unroll
      for (int i = 0; i < 4; i++) *(uint4*)&u[i * 4] = pb[i];
#pragma unroll
      for (int j = 0; j < 8; j++) {
        bh[j] = (u[2 * j] & 0xffffu) | (u[2 * j + 1] << 16);
        bl[j] = (u[2 * j] >> 16) | (u[2 * j + 1] & 0xffff0000u);
      }
      *(uint4*)&Bhi[sr][sk]     = *(uint4*)&bh[0];
      *(uint4*)&Bhi[sr][sk + 8] = *(uint4*)&bh[4];
      *(uint4*)&Blo[sr][sk]     = *(uint4*)&bl[0];
      *(uint4*)&Blo[sr][sk + 8] = *(uint4*)&bl[4];
    }
  };

  load_tile(0);
  for (int k0 = 0; k0 < K; k0 += 32) {
    commit_tile();
    bar_lds();                               // flush ds_writes; loads may remain in flight
    if (k0 + 32 < K) load_tile(k0 + 32);     // next tile's loads span the next barrier

    bf16x8 bh[4], bl[4];
#pragma unroll
    for (int j = 0; j < 4; j++) {
      bh[j] = *(const bf16x8*)&Bhi[wc * 64 + j * 16 + lrow][kgrp];
      bl[j] = *(const bf16x8*)&Blo[wc * 64 + j * 16 + lrow][kgrp];
    }
#pragma unroll
    for (int i = 0; i < 4; i++) {
      bf16x8 ah = *(const bf16x8*)&Ahi[wr * 64 + i * 16 + lrow][kgrp];
      bf16x8 al = *(const bf16x8*)&Alo[wr * 64 + i * 16 + lrow][kgrp];
#pragma unroll
      for (int j = 0; j < 4; j++) {
        acc[i][j] = __builtin_amdgcn_mfma_f32_16x16x32_bf16(ah, bh[j], acc[i][j], 0, 0, 0);
        acc[i][j] = __builtin_amdgcn_mfma_f32_16x16x32_bf16(ah, bl[j], acc[i][j], 0, 0, 0);
        acc[i][j] = __builtin_amdgcn_mfma_f32_16x16x32_bf16(al, bh[j], acc[i][j], 0, 0, 0);
      }
    }
    bar_lds();                               // frag reads done; prefetch still in flight
  }

  const int crow4 = (l >> 4) * 4;
#pragma unroll
  for (int i = 0; i < 4; i++) {
#pragma unroll
    for (int j = 0; j < 4; j++) {
      const int col = col0 + wc * 64 + j * 16 + lrow;
      const float bv = bias[col];
      const int rowb = row0 + wr * 64 + i * 16 + crow4;
#pragma unroll
      for (int r = 0; r < 4; r++) {
        float v = acc[i][j][r] + bv;
        size_t off = (size_t)(rowb + r) * N + col;
        if (C_PACKED) ((uint32_t*)Cv)[off] = pack_split(v);
        else          ((float*)Cv)[off] = v;
      }
    }
  }
}

// ---------- fp32 VALU GEMM (tiny N=48 param GEMM) ----------
__global__ __launch_bounds__(256) void gemm_f32(
    const float* __restrict__ A, int lda,
    const float* __restrict__ W,
    const float* __restrict__ bias,
    float* __restrict__ C, int M, int N, int K) {
  __shared__ float As[16][132];
  __shared__ float Bs[16][128];
  const int tid  = threadIdx.x;
  const int row0 = blockIdx.y * 128;
  const int col0 = blockIdx.x * 128;
  const int ty = tid >> 4;
  const int tx = tid & 15;
  const int a_r = tid >> 2;
  const int a_k = (tid & 3) << 2;
  const int b_r = tid >> 5;
  const int b_c = (tid & 31) << 2;

  float acc[8][8];
#pragma unroll
  for (int i = 0; i < 8; i++)
#pragma unroll
    for (int j = 0; j < 8; j++) acc[i][j] = 0.f;

  float4 areg[2], breg[2];
  const int gc = col0 + b_c;
#pragma unroll
  for (int i = 0; i < 2; i++)
    areg[i] = *(const float4*)(A + (size_t)(row0 + a_r + i * 64) * lda + a_k);
#pragma unroll
  for (int i = 0; i < 2; i++) {
    breg[i] = make_float4(0.f, 0.f, 0.f, 0.f);
    if (gc < N) breg[i] = *(const float4*)(W + (size_t)(b_r + i * 8) * N + gc);
  }

  for (int k0 = 0; k0 < K; k0 += 16) {
#pragma unroll
    for (int i = 0; i < 2; i++) {
      int r = a_r + i * 64;
      As[a_k + 0][r] = areg[i].x;
      As[a_k + 1][r] = areg[i].y;
      As[a_k + 2][r] = areg[i].z;
      As[a_k + 3][r] = areg[i].w;
    }
#pragma unroll
    for (int i = 0; i < 2; i++) *(float4*)(&Bs[b_r + i * 8][b_c]) = breg[i];
    bar_lds();

    if (k0 + 16 < K) {
#pragma unroll
      for (int i = 0; i < 2; i++)
        areg[i] = *(const float4*)(A + (size_t)(row0 + a_r + i * 64) * lda + (k0 + 16 + a_k));
#pragma unroll
      for (int i = 0; i < 2; i++) {
        breg[i] = make_float4(0.f, 0.f, 0.f, 0.f);
        if (gc < N) breg[i] = *(const float4*)(W + (size_t)(k0 + 16 + b_r + i * 8) * N + gc);
      }
    }

#pragma unroll
    for (int kk = 0; kk < 16; kk++) {
      float af[8], bf[8];
      *(float4*)&af[0] = *(const float4*)&As[kk][ty * 8];
      *(float4*)&af[4] = *(const float4*)&As[kk][ty * 8 + 4];
      *(float4*)&bf[0] = *(const float4*)&Bs[kk][tx * 8];
      *(float4*)&bf[4] = *(const float4*)&Bs[kk][tx * 8 + 4];
#pragma unroll
      for (int i = 0; i < 8; i++)
#pragma unroll
        for (int j = 0; j < 8; j++) acc[i][j] += af[i] * bf[j];
    }
    bar_lds();
  }
#pragma unroll
  for (int i = 0; i < 8; i++) {
    int r = row0 + ty * 8 + i;
#pragma unroll
    for (int j0 = 0; j0 < 8; j0 += 4) {
      int cc = col0 + tx * 8 + j0;
      if (cc < N) {
        float4 ov;
        ov.x = acc[i][j0 + 0] + bias[cc + 0];
        ov.y = acc[i][j0 + 1] + bias[cc + 1];
        ov.z = acc[i][j0 + 2] + bias[cc + 2];
        ov.w = acc[i][j0 + 3] + bias[cc + 3];
        *(float4*)(C + (size_t)r * N + cc) = ov;
      }
    }
  }
}

// L2-normalize packed q/k rows (length 64) in-place. One wave per row.
__global__ __launch_bounds__(256) void normalize_qk(uint32_t* __restrict__ qkv) {
  const int idx = blockIdx.x * 4 + (threadIdx.x >> 6);
  const int l = threadIdx.x & 63;
  const int rowBT = idx >> 5;
  const int rem = idx & 31;
  const int which = rem >> 4;
  const int h = rem & 15;
  const size_t addr = (size_t)rowBT * 3072 + (size_t)which * 1024 + h * 64 + l;
  float v = unpack_f(qkv[addr]);
  float ss = wave_sum(v * v);
  float sc = 1.f / fmaxf(sqrtf(ss), 1e-12f);
  qkv[addr] = pack_split(v * sc);
}

// Titans recurrence (r7 structure, 539 µs) with lgkm-only barriers: the phase-A
// global o-stores and phase-C prefetch loads no longer drain at each barrier.
__global__ __launch_bounds__(512) void titans_rec(
    uint32_t* __restrict__ qkv, const float* __restrict__ p,
    const float* __restrict__ w, const float* __restrict__ bparm) {
  const int bh = blockIdx.x;
  const int b = bh >> 4;
  const int h = bh & 15;
  const int tid = threadIdx.x;
  const int wv = tid >> 6;   // 0..7
  const int l = tid & 63;

  __shared__ float k_s[2][CSZ][DD];
  __shared__ float q_s[2][CSZ][DD];
  __shared__ float v_s[CSZ][DD];
  __shared__ float dkh_s[CSZ][DD];
  __shared__ float part[2][WVS][CSZ][DD];
  __shared__ float4 prm_s[2][CSZ];

  f32x2 S2[4], M2[4];
#pragma unroll
  for (int r = 0; r < 4; r++) { S2[r] = (f32x2){0.f, 0.f}; M2[r] = (f32x2){0.f, 0.f}; }

  const float w_l = w[h * DD + l];
  const float b_l = bparm[h * DD + l];

  uint32_t* qbase = qkv + (size_t)(b * TT) * 3072 + h * DD;
  const float* pbase = p + (size_t)(b * TT) * 48 + h * 3;

  uint32_t rq[2], rk[2], rv[2];
  float rp0 = 0.f, rp1 = 0.f, rp2 = 0.f;
  // ---- prologue: load + commit chunk 0; load chunk 1 into regs ----
  {
#pragma unroll
    for (int i = 0; i < 2; i++) {
      const int row = wv + i * 8;
      size_t roff = (size_t)row * 3072 + l;
      q_s[0][row][l] = unpack_f(qbase[roff]);
      k_s[0][row][l] = unpack_f(qbase[roff + 1024]);
      v_s[row][l]    = unpack_f(qbase[roff + 2048]);
    }
    if (tid < CSZ) {
      const float* pp = pbase + (size_t)tid * 48;
      prm_s[0][tid] = make_float4(sigmoidf_(pp[0]), sigmoidf_(pp[1]), sigmoidf_(pp[2]), 0.f);
    }
#pragma unroll
    for (int i = 0; i < 2; i++) {
      size_t roff = (size_t)(CSZ + wv + i * 8) * 3072 + l;
      rq[i] = qbase[roff];
      rk[i] = qbase[roff + 1024];
      rv[i] = qbase[roff + 2048];
    }
    if (tid < CSZ) {
      const float* pp = pbase + (size_t)(CSZ + tid) * 48;
      rp0 = pp[0]; rp1 = pp[1]; rp2 = pp[2];
    }
  }
  bar_lds();

  for (int nt = 0; nt < NTC; nt++) {
    const int buf = nt & 1;
    float (*partw)[CSZ][DD] = part[buf];       // this chunk's kh, then po
    float (*partr)[CSZ][DD] = part[buf ^ 1];   // previous chunk's po

    // ---- phase A: deferred o/LN/store of chunk nt-1, then kh partials (packed) ----
    if (nt > 0) {
#pragma unroll
      for (int i = 0; i < 2; i++) {
        const int t = wv + i * 8;
        float o = 0.f;
#pragma unroll
        for (int ww = 0; ww < WVS; ww++) o += partr[ww][t][l];
        float mu = wave_sum(o) * (1.f / 64.f);
        float xc = o - mu;
        float var = wave_sum(xc * xc) * (1.f / 64.f);
        float rstd = rsqrtf(var + EPSF);
        float y = xc * rstd * w_l + b_l;
        qbase[(size_t)((nt - 1) * CSZ + t) * 3072 + 2048 + l] = pack_split(y);
      }
    }
#pragma unroll
    for (int c = 0; c < CSZ; c++) {
      const f32x2* kp2 = (const f32x2*)&k_s[buf][c][wv * 8];
      f32x2 a2;
      a2 = kp2[0] * S2[0];
      a2 = kp2[1] * S2[1] + a2;
      a2 = kp2[2] * S2[2] + a2;
      a2 = kp2[3] * S2[3] + a2;
      partw[wv][c][l] = a2.x + a2.y;
    }
    bar_lds();

    // ---- phase B: LN fwd + bwd — two token rows per wave ----
#pragma unroll
    for (int i = 0; i < 2; i++) {
      const int c = wv + i * 8;
      float kh = 0.f;
#pragma unroll
      for (int ww = 0; ww < WVS; ww++) kh += partw[ww][c][l];
      float mu = wave_sum(kh) * (1.f / 64.f);
      float xc = kh - mu;
      float var = wave_sum(xc * xc) * (1.f / 64.f);
      float rstd = rsqrtf(var + EPSF);
      float xhat = xc * rstd;
      float y = xhat * w_l + b_l;
      float dy = 2.f * (y - v_s[c][l]);
      float wdy = dy * w_l;
      float c1 = wave_sum(xhat * wdy) * (1.f / 64.f);
      float c2 = wave_sum(wdy) * (1.f / 64.f);
      dkh_s[c][l] = (wdy - xhat * c1 - c2) * rstd;
    }
    bar_lds();

    // ---- phase C: commit next tiles, issue prefetch, token scan (packed) ----
    if (nt + 1 < NTC) {
#pragma unroll
      for (int i = 0; i < 2; i++) {
        const int row = wv + i * 8;
        k_s[buf ^ 1][row][l] = unpack_f(rk[i]);
        q_s[buf ^ 1][row][l] = unpack_f(rq[i]);
        v_s[row][l] = unpack_f(rv[i]);
      }
      if (tid < CSZ)
        prm_s[buf ^ 1][tid] = make_float4(sigmoidf_(rp0), sigmoidf_(rp1), sigmoidf_(rp2), 0.f);
    }
    if (nt + 2 < NTC) {
#pragma unroll
      for (int i = 0; i < 2; i++) {
        size_t roff = (size_t)((nt + 2) * CSZ + wv + i * 8) * 3072 + l;
        rq[i] = qbase[roff];
        rk[i] = qbase[roff + 1024];
        rv[i] = qbase[roff + 2048];
      }
      if (tid < CSZ) {
        const float* pp = pbase + (size_t)((nt + 2) * CSZ + tid) * 48;
        rp0 = pp[0]; rp1 = pp[1]; rp2 = pp[2];
      }
    }
#pragma unroll
    for (int t = 0; t < CSZ; t++) {
      float4 prm = prm_s[buf][t];
      float a = prm.x * dkh_s[t][l];
      const f32x2 na2 = (f32x2){-a, -a};
      const f32x2 et2 = (f32x2){prm.z, prm.z};
      const f32x2 be2 = (f32x2){1.f - prm.y, 1.f - prm.y};
      const f32x2* kp2 = (const f32x2*)&k_s[buf][t][wv * 8];
      const f32x2* qp2 = (const f32x2*)&q_s[buf][t][wv * 8];
      f32x2 po2 = (f32x2){0.f, 0.f};
#pragma unroll
      for (int pq = 0; pq < 4; pq++) {
        M2[pq] = et2 * M2[pq] + na2 * kp2[pq];   // pk_mul + pk_fma
        S2[pq] = be2 * S2[pq] + M2[pq];          // pk_fma
        po2    = qp2[pq] * S2[pq] + po2;         // pk_fma
      }
      partw[wv][t][l] = po2.x + po2.y;
    }
    bar_lds();
  }

  // ---- epilogue: deferred D for the last chunk ----
  {
    float (*partr)[CSZ][DD] = part[(NTC - 1) & 1];
#pragma unroll
    for (int i = 0; i < 2; i++) {
      const int t = wv + i * 8;
      float o = 0.f;
#pragma unroll
      for (int ww = 0; ww < WVS; ww++) o += partr[ww][t][l];
      float mu = wave_sum(o) * (1.f / 64.f);
      float xc = o - mu;
      float var = wave_sum(xc * xc) * (1.f / 64.f);
      float rstd = rsqrtf(var + EPSF);
      float y = xc * rstd * w_l + b_l;
      qbase[(size_t)((NTC - 1) * CSZ + t) * 3072 + 2048 + l] = pack_split(y);
    }
  }
}

extern "C" void kernel_launch(void* const* d_in, const int* in_sizes, int n_in,
                              void* d_out, int out_size, void* d_ws, size_t ws_size,
                              hipStream_t stream) {
  const float* x      = (const float*)d_in[0];
  const float* W_attn = (const float*)d_in[1];
  const float* b_attn = (const float*)d_in[2];
  const float* W_parm = (const float*)d_in[3];
  const float* b_parm = (const float*)d_in[4];
  const float* W_proj = (const float*)d_in[5];
  const float* b_proj = (const float*)d_in[6];
  const float* w      = (const float*)d_in[7];
  const float* bb     = (const float*)d_in[8];
  float* out = (float*)d_out;

  const int M = BB * TT;        // 8192
  float* qkv = (float*)d_ws;                               // M x 3072 (packed u32)
  float* pbf = qkv + (size_t)M * 3072;                     // M x 48 f32
  uint32_t* wattn_t = (uint32_t*)(pbf + (size_t)M * 48);   // 3072 x 1024 packed
  uint32_t* wproj_t = wattn_t + (size_t)3072 * 1024;       // 1024 x 1024 packed

  split_transpose<<<dim3(3072 / 32, 1024 / 32), 256, 0, stream>>>(W_attn, wattn_t, 1024, 3072);
  split_transpose<<<dim3(1024 / 32, 1024 / 32), 256, 0, stream>>>(W_proj, wproj_t, 1024, 1024);

  gemm_split<false, true><<<dim3(3072 / 128, M / 128), 256, 0, stream>>>(
      x, CCH, wattn_t, b_attn, qkv, M, 3072, CCH);
  gemm_f32<<<dim3(1, M / 128), 256, 0, stream>>>(x, CCH, W_parm, b_parm, pbf, M, 48, CCH);
  normalize_qk<<<(M * 2 * HH) / 4, 256, 0, stream>>>((uint32_t*)qkv);
  titans_rec<<<BB * HH, 512, 0, stream>>>((uint32_t*)qkv, pbf, w, bb);
  gemm_split<true, false><<<dim3(CCH / 128, M / 128), 256, 0, stream>>>(
      (uint32_t*)qkv + 2048, 3072, wproj_t, b_proj, out, M, CCH, CCH);
}

// Round 9
// 954.557 us; speedup vs baseline: 1.2970x; 1.0240x over previous
//
#include <hip/hip_runtime.h>
#include <cstddef>
#include <cstdint>
#include <math.h>

#define BB   4
#define TT   2048
#define CCH  1024
#define HH   16
#define DD   64
#define CSZ  16
#define NTC  128
#define EPSF 1e-5f
#define WVS  8
#define STR  3120   // qkv row stride: q[0,1024) k[1024,2048) v[2048,3072) p[3072,3120)

typedef __attribute__((ext_vector_type(8))) short bf16x8;
typedef __attribute__((ext_vector_type(4))) float f32x4;
typedef __attribute__((ext_vector_type(2))) float f32x2;

// Barrier that flushes LDS ops only. Global stores / register prefetch loads stay
// in flight across the barrier (guide T4); compiler still inserts vmcnt(N) before
// each use of a prefetched register.
__device__ __forceinline__ void bar_lds() {
  asm volatile("s_waitcnt lgkmcnt(0)" ::: "memory");
  __builtin_amdgcn_s_barrier();
}

// ---------- split-float helpers: f32 ≈ hi(bf16) + lo(bf16), packed (hi | lo<<16) ----------
__device__ __forceinline__ uint32_t pack_split(float f) {
  uint32_t b = __float_as_uint(f);
  uint32_t uh = (b + 0x7fffu + ((b >> 16) & 1u)) >> 16;   // RNE bf16 of f
  float fh = __uint_as_float(uh << 16);
  float r = f - fh;
  return uh | (__float_as_uint(r) & 0xffff0000u);          // lo = trunc bf16 of residual
}
__device__ __forceinline__ float unpack_f(uint32_t u) {
  return __uint_as_float(u << 16) + __uint_as_float(u & 0xffff0000u);
}

// Wave64 sum via DPP (VALU pipe).
__device__ __forceinline__ float wave_sum(float x) {
  float v = x;
  v += __int_as_float(__builtin_amdgcn_update_dpp(0, __float_as_int(v), 0x111, 0xf, 0xf, true));
  v += __int_as_float(__builtin_amdgcn_update_dpp(0, __float_as_int(v), 0x112, 0xf, 0xf, true));
  v += __int_as_float(__builtin_amdgcn_update_dpp(0, __float_as_int(v), 0x114, 0xf, 0xf, true));
  v += __int_as_float(__builtin_amdgcn_update_dpp(0, __float_as_int(v), 0x118, 0xf, 0xf, true));
  v += __int_as_float(__builtin_amdgcn_update_dpp(0, __float_as_int(v), 0x142, 0xa, 0xf, true));
  v += __int_as_float(__builtin_amdgcn_update_dpp(0, __float_as_int(v), 0x143, 0xc, 0xf, true));
  return __int_as_float(__builtin_amdgcn_readlane(__float_as_int(v), 63));
}

// Sum across a 16-lane group (all 16 lanes end with the total): DPP butterfly
// quad_perm xor1 (0xB1), quad_perm xor2 (0x4E), row_ror:4, row_ror:8.
__device__ __forceinline__ float red16(float x) {
  float v = x;
  v += __int_as_float(__builtin_amdgcn_update_dpp(0, __float_as_int(v), 0x0B1, 0xf, 0xf, true));
  v += __int_as_float(__builtin_amdgcn_update_dpp(0, __float_as_int(v), 0x04E, 0xf, 0xf, true));
  v += __int_as_float(__builtin_amdgcn_update_dpp(0, __float_as_int(v), 0x124, 0xf, 0xf, true));
  v += __int_as_float(__builtin_amdgcn_update_dpp(0, __float_as_int(v), 0x128, 0xf, 0xf, true));
  return v;
}

__device__ __forceinline__ float sigmoidf_(float x) {
  return 1.f / (1.f + expf(-x));
}

// ---------- transpose + split: W (KxN f32) -> Wt rows [rowOff, rowOff+N) (xK packed u32) ----------
__global__ __launch_bounds__(256) void split_transpose(
    const float* __restrict__ W, uint32_t* __restrict__ Wt, int K, int N, int rowOff) {
  __shared__ float t[32][33];
  const int n0 = blockIdx.x * 32, k0 = blockIdx.y * 32;
  const int tx = threadIdx.x & 31, ty = threadIdx.x >> 5;  // ty 0..7
#pragma unroll
  for (int i = 0; i < 4; i++) {
    int n = n0 + tx;
    t[ty + i * 8][tx] = (n < N) ? W[(size_t)(k0 + ty + i * 8) * N + n] : 0.f;
  }
  __syncthreads();
#pragma unroll
  for (int i = 0; i < 4; i++) {
    int n = n0 + ty + i * 8;
    if (n < N)
      Wt[(size_t)(rowOff + n) * K + k0 + tx] = pack_split(t[tx][ty + i * 8]);
  }
}

// ---------- split-bf16 MFMA GEMM: C = A @ Bt^T + bias ----------
// Bt rows >= Nb are treated as zero (staging guard). Stores guarded to col < Ns.
// C_PACKED: cols < pklim stored as pack_split, cols >= pklim as raw f32 bits.
// NORM: blocks with col0 < 2048 L2-normalize each 64-col head-row before packing
// (row's 64 cols = 4 j-frags x 16 lanes -> red16 butterfly, no LDS).
template<bool A_PACKED, bool C_PACKED, bool NORM>
__global__ __launch_bounds__(256) void gemm_split(
    const void* __restrict__ Av, int lda,
    const uint32_t* __restrict__ Bt,
    const float* __restrict__ bias,
    void* __restrict__ Cv, int M, int ldc, int K, int Nb, int Ns, int pklim) {
  __shared__ unsigned short Ahi[128][40];
  __shared__ unsigned short Alo[128][40];
  __shared__ unsigned short Bhi[128][40];
  __shared__ unsigned short Blo[128][40];

  const int tid = threadIdx.x;
  const int row0 = blockIdx.y * 128;
  const int col0 = blockIdx.x * 128;
  const int wv = tid >> 6;
  const int l  = tid & 63;
  const int wr = wv >> 1, wc = wv & 1;
  const int lrow = l & 15;
  const int kgrp = (l >> 4) * 8;

  const int sr = tid >> 1;
  const int sk = (tid & 1) * 16;

  f32x4 acc[4][4];
#pragma unroll
  for (int i = 0; i < 4; i++)
#pragma unroll
    for (int j = 0; j < 4; j++) acc[i][j] = (f32x4){0.f, 0.f, 0.f, 0.f};

  uint4 pa[4];    // A_PACKED: 16 packed u32
  float4 pf[4];   // !A_PACKED: 16 floats
  uint4 pb[4];    // B: 16 packed u32

  auto load_tile = [&](int k0) {
    if (A_PACKED) {
      const uint32_t* Ap = (const uint32_t*)Av + (size_t)(row0 + sr) * lda + k0 + sk;
#pragma unroll
      for (int i = 0; i < 4; i++) pa[i] = *(const uint4*)(Ap + i * 4);
    } else {
      const float* Ap = (const float*)Av + (size_t)(row0 + sr) * lda + k0 + sk;
#pragma unroll
      for (int i = 0; i < 4; i++) pf[i] = *(const float4*)(Ap + i * 4);
    }
    if (col0 + sr < Nb) {
      const uint32_t* Bp = Bt + (size_t)(col0 + sr) * K + k0 + sk;
#pragma unroll
      for (int i = 0; i < 4; i++) pb[i] = *(const uint4*)(Bp + i * 4);
    } else {
#pragma unroll
      for (int i = 0; i < 4; i++) pb[i] = make_uint4(0u, 0u, 0u, 0u);
    }
  };

  auto commit_tile = [&]() {
    uint32_t hp[8], lp[8];
    if (A_PACKED) {
      uint32_t u[16];
#pragma unroll
      for (int i = 0; i < 4; i++) *(uint4*)&u[i * 4] = pa[i];
#pragma unroll
      for (int j = 0; j < 8; j++) {
        hp[j] = (u[2 * j] & 0xffffu) | (u[2 * j + 1] << 16);
        lp[j] = (u[2 * j] >> 16) | (u[2 * j + 1] & 0xffff0000u);
      }
    } else {
      float f[16];
#pragma unroll
      for (int i = 0; i < 4; i++) *(float4*)&f[i * 4] = pf[i];
      uint32_t uh[16], ulr[16];
#pragma unroll
      for (int j = 0; j < 16; j++) {
        uint32_t b = __float_as_uint(f[j]);
        uint32_t h = (b + 0x7fffu + ((b >> 16) & 1u)) >> 16;
        uh[j] = h;
        ulr[j] = __float_as_uint(f[j] - __uint_as_float(h << 16));
      }
#pragma unroll
      for (int j = 0; j < 8; j++) {
        hp[j] = uh[2 * j] | (uh[2 * j + 1] << 16);
        lp[j] = (ulr[2 * j] >> 16) | (ulr[2 * j + 1] & 0xffff0000u);
      }
    }
    *(uint4*)&Ahi[sr][sk]     = *(uint4*)&hp[0];
    *(uint4*)&Ahi[sr][sk + 8] = *(uint4*)&hp[4];
    *(uint4*)&Alo[sr][sk]     = *(uint4*)&lp[0];
    *(uint4*)&Alo[sr][sk + 8] = *(uint4*)&lp[4];
    {
      uint32_t u[16], bh[8], bl[8];
#pragma unroll
      for (int i = 0; i < 4; i++) *(uint4*)&u[i * 4] = pb[i];
#pragma unroll
      for (int j = 0; j < 8; j++) {
        bh[j] = (u[2 * j] & 0xffffu) | (u[2 * j + 1] << 16);
        bl[j] = (u[2 * j] >> 16) | (u[2 * j + 1] & 0xffff0000u);
      }
      *(uint4*)&Bhi[sr][sk]     = *(uint4*)&bh[0];
      *(uint4*)&Bhi[sr][sk + 8] = *(uint4*)&bh[4];
      *(uint4*)&Blo[sr][sk]     = *(uint4*)&bl[0];
      *(uint4*)&Blo[sr][sk + 8] = *(uint4*)&bl[4];
    }
  };

  load_tile(0);
  for (int k0 = 0; k0 < K; k0 += 32) {
    commit_tile();
    bar_lds();                               // flush ds_writes; vmem stays in flight
    if (k0 + 32 < K) load_tile(k0 + 32);     // spans the next barrier

    bf16x8 bh[4], bl[4];
#pragma unroll
    for (int j = 0; j < 4; j++) {
      bh[j] = *(const bf16x8*)&Bhi[wc * 64 + j * 16 + lrow][kgrp];
      bl[j] = *(const bf16x8*)&Blo[wc * 64 + j * 16 + lrow][kgrp];
    }
#pragma unroll
    for (int i = 0; i < 4; i++) {
      bf16x8 ah = *(const bf16x8*)&Ahi[wr * 64 + i * 16 + lrow][kgrp];
      bf16x8 al = *(const bf16x8*)&Alo[wr * 64 + i * 16 + lrow][kgrp];
#pragma unroll
      for (int j = 0; j < 4; j++) {
        acc[i][j] = __builtin_amdgcn_mfma_f32_16x16x32_bf16(ah, bh[j], acc[i][j], 0, 0, 0);
        acc[i][j] = __builtin_amdgcn_mfma_f32_16x16x32_bf16(ah, bl[j], acc[i][j], 0, 0, 0);
        acc[i][j] = __builtin_amdgcn_mfma_f32_16x16x32_bf16(al, bh[j], acc[i][j], 0, 0, 0);
      }
    }
    bar_lds();
  }

  // ---- epilogue: C/D layout col=lane&15, row=(lane>>4)*4+reg ----
  const int crow4 = (l >> 4) * 4;
  if (NORM && col0 < 2048) {
    // q/k rows: normalize each head-row (64 cols) in-register.
    float bj[4];
#pragma unroll
    for (int j = 0; j < 4; j++) bj[j] = bias[col0 + wc * 64 + j * 16 + lrow];
#pragma unroll
    for (int i = 0; i < 4; i++) {
#pragma unroll
      for (int r = 0; r < 4; r++) {
        float vals[4];
        float ss = 0.f;
#pragma unroll
        for (int j = 0; j < 4; j++) {
          vals[j] = acc[i][j][r] + bj[j];
          ss += vals[j] * vals[j];
        }
        ss = red16(ss);
        float sc = 1.f / fmaxf(sqrtf(ss), 1e-12f);
        const int rowb = row0 + wr * 64 + i * 16 + crow4 + r;
#pragma unroll
        for (int j = 0; j < 4; j++) {
          const int col = col0 + wc * 64 + j * 16 + lrow;
          ((uint32_t*)Cv)[(size_t)rowb * ldc + col] = pack_split(vals[j] * sc);
        }
      }
    }
  } else {
#pragma unroll
    for (int i = 0; i < 4; i++) {
#pragma unroll
      for (int j = 0; j < 4; j++) {
        const int col = col0 + wc * 64 + j * 16 + lrow;
        const float bv = (col < Ns) ? bias[col] : 0.f;
        const int rowb = row0 + wr * 64 + i * 16 + crow4;
#pragma unroll
        for (int r = 0; r < 4; r++) {
          float v = acc[i][j][r] + bv;
          size_t off = (size_t)(rowb + r) * ldc + col;
          if (col < Ns) {
            if (C_PACKED) {
              uint32_t word = (col < pklim) ? pack_split(v) : __float_as_uint(v);
              ((uint32_t*)Cv)[off] = word;
            } else {
              ((float*)Cv)[off] = v;
            }
          }
        }
      }
    }
  }
}

// Titans recurrence (r8-proven, 539 µs). One block per (b,h), 512 threads = 8 waves
// x 8 S-rows; packed-fp32 (pk_fma) hot loops; lgkm-only barriers. q/k arrive already
// L2-normalized (fused into the qkv GEMM epilogue); p lives as raw f32 in qkv cols
// 3072..3119 (sigmoid applied here).
__global__ __launch_bounds__(512) void titans_rec(
    uint32_t* __restrict__ qkv,
    const float* __restrict__ w, const float* __restrict__ bparm) {
  const int bh = blockIdx.x;
  const int b = bh >> 4;
  const int h = bh & 15;
  const int tid = threadIdx.x;
  const int wv = tid >> 6;   // 0..7
  const int l = tid & 63;

  __shared__ float k_s[2][CSZ][DD];
  __shared__ float q_s[2][CSZ][DD];
  __shared__ float v_s[CSZ][DD];
  __shared__ float dkh_s[CSZ][DD];
  __shared__ float part[2][WVS][CSZ][DD];
  __shared__ float4 prm_s[2][CSZ];

  f32x2 S2[4], M2[4];
#pragma unroll
  for (int r = 0; r < 4; r++) { S2[r] = (f32x2){0.f, 0.f}; M2[r] = (f32x2){0.f, 0.f}; }

  const float w_l = w[h * DD + l];
  const float b_l = bparm[h * DD + l];

  uint32_t* qbase = qkv + (size_t)(b * TT) * STR + h * DD;
  const float* pbase = (const float*)qkv + (size_t)(b * TT) * STR + 3072 + h * 3;

  uint32_t rq[2], rk[2], rv[2];
  float rp0 = 0.f, rp1 = 0.f, rp2 = 0.f;
  // ---- prologue: load + commit chunk 0; load chunk 1 into regs ----
  {
#pragma unroll
    for (int i = 0; i < 2; i++) {
      const int row = wv + i * 8;
      size_t roff = (size_t)row * STR + l;
      q_s[0][row][l] = unpack_f(qbase[roff]);
      k_s[0][row][l] = unpack_f(qbase[roff + 1024]);
      v_s[row][l]    = unpack_f(qbase[roff + 2048]);
    }
    if (tid < CSZ) {
      const float* pp = pbase + (size_t)tid * STR;
      prm_s[0][tid] = make_float4(sigmoidf_(pp[0]), sigmoidf_(pp[1]), sigmoidf_(pp[2]), 0.f);
    }
#pragma unroll
    for (int i = 0; i < 2; i++) {
      size_t roff = (size_t)(CSZ + wv + i * 8) * STR + l;
      rq[i] = qbase[roff];
      rk[i] = qbase[roff + 1024];
      rv[i] = qbase[roff + 2048];
    }
    if (tid < CSZ) {
      const float* pp = pbase + (size_t)(CSZ + tid) * STR;
      rp0 = pp[0]; rp1 = pp[1]; rp2 = pp[2];
    }
  }
  bar_lds();

  for (int nt = 0; nt < NTC; nt++) {
    const int buf = nt & 1;
    float (*partw)[CSZ][DD] = part[buf];       // this chunk's kh, then po
    float (*partr)[CSZ][DD] = part[buf ^ 1];   // previous chunk's po

    // ---- phase A: deferred o/LN/store of chunk nt-1, then kh partials (packed) ----
    if (nt > 0) {
#pragma unroll
      for (int i = 0; i < 2; i++) {
        const int t = wv + i * 8;
        float o = 0.f;
#pragma unroll
        for (int ww = 0; ww < WVS; ww++) o += partr[ww][t][l];
        float mu = wave_sum(o) * (1.f / 64.f);
        float xc = o - mu;
        float var = wave_sum(xc * xc) * (1.f / 64.f);
        float rstd = rsqrtf(var + EPSF);
        float y = xc * rstd * w_l + b_l;
        qbase[(size_t)((nt - 1) * CSZ + t) * STR + 2048 + l] = pack_split(y);
      }
    }
#pragma unroll
    for (int c = 0; c < CSZ; c++) {
      const f32x2* kp2 = (const f32x2*)&k_s[buf][c][wv * 8];
      f32x2 a2;
      a2 = kp2[0] * S2[0];
      a2 = kp2[1] * S2[1] + a2;
      a2 = kp2[2] * S2[2] + a2;
      a2 = kp2[3] * S2[3] + a2;
      partw[wv][c][l] = a2.x + a2.y;
    }
    bar_lds();

    // ---- phase B: LN fwd + bwd — two token rows per wave ----
#pragma unroll
    for (int i = 0; i < 2; i++) {
      const int c = wv + i * 8;
      float kh = 0.f;
#pragma unroll
      for (int ww = 0; ww < WVS; ww++) kh += partw[ww][c][l];
      float mu = wave_sum(kh) * (1.f / 64.f);
      float xc = kh - mu;
      float var = wave_sum(xc * xc) * (1.f / 64.f);
      float rstd = rsqrtf(var + EPSF);
      float xhat = xc * rstd;
      float y = xhat * w_l + b_l;
      float dy = 2.f * (y - v_s[c][l]);
      float wdy = dy * w_l;
      float c1 = wave_sum(xhat * wdy) * (1.f / 64.f);
      float c2 = wave_sum(wdy) * (1.f / 64.f);
      dkh_s[c][l] = (wdy - xhat * c1 - c2) * rstd;
    }
    bar_lds();

    // ---- phase C: commit next tiles, issue prefetch, token scan (packed) ----
    if (nt + 1 < NTC) {
#pragma unroll
      for (int i = 0; i < 2; i++) {
        const int row = wv + i * 8;
        k_s[buf ^ 1][row][l] = unpack_f(rk[i]);
        q_s[buf ^ 1][row][l] = unpack_f(rq[i]);
        v_s[row][l] = unpack_f(rv[i]);
      }
      if (tid < CSZ)
        prm_s[buf ^ 1][tid] = make_float4(sigmoidf_(rp0), sigmoidf_(rp1), sigmoidf_(rp2), 0.f);
    }
    if (nt + 2 < NTC) {
#pragma unroll
      for (int i = 0; i < 2; i++) {
        size_t roff = (size_t)((nt + 2) * CSZ + wv + i * 8) * STR + l;
        rq[i] = qbase[roff];
        rk[i] = qbase[roff + 1024];
        rv[i] = qbase[roff + 2048];
      }
      if (tid < CSZ) {
        const float* pp = pbase + (size_t)((nt + 2) * CSZ + tid) * STR;
        rp0 = pp[0]; rp1 = pp[1]; rp2 = pp[2];
      }
    }
#pragma unroll
    for (int t = 0; t < CSZ; t++) {
      float4 prm = prm_s[buf][t];
      float a = prm.x * dkh_s[t][l];
      const f32x2 na2 = (f32x2){-a, -a};
      const f32x2 et2 = (f32x2){prm.z, prm.z};
      const f32x2 be2 = (f32x2){1.f - prm.y, 1.f - prm.y};
      const f32x2* kp2 = (const f32x2*)&k_s[buf][t][wv * 8];
      const f32x2* qp2 = (const f32x2*)&q_s[buf][t][wv * 8];
      f32x2 po2 = (f32x2){0.f, 0.f};
#pragma unroll
      for (int pq = 0; pq < 4; pq++) {
        M2[pq] = et2 * M2[pq] + na2 * kp2[pq];   // pk_mul + pk_fma
        S2[pq] = be2 * S2[pq] + M2[pq];          // pk_fma
        po2    = qp2[pq] * S2[pq] + po2;         // pk_fma
      }
      partw[wv][t][l] = po2.x + po2.y;
    }
    bar_lds();
  }

  // ---- epilogue: deferred D for the last chunk ----
  {
    float (*partr)[CSZ][DD] = part[(NTC - 1) & 1];
#pragma unroll
    for (int i = 0; i < 2; i++) {
      const int t = wv + i * 8;
      float o = 0.f;
#pragma unroll
      for (int ww = 0; ww < WVS; ww++) o += partr[ww][t][l];
      float mu = wave_sum(o) * (1.f / 64.f);
      float xc = o - mu;
      float var = wave_sum(xc * xc) * (1.f / 64.f);
      float rstd = rsqrtf(var + EPSF);
      float y = xc * rstd * w_l + b_l;
      qbase[(size_t)((NTC - 1) * CSZ + t) * STR + 2048 + l] = pack_split(y);
    }
  }
}

extern "C" void kernel_launch(void* const* d_in, const int* in_sizes, int n_in,
                              void* d_out, int out_size, void* d_ws, size_t ws_size,
                              hipStream_t stream) {
  const float* x      = (const float*)d_in[0];
  const float* W_attn = (const float*)d_in[1];
  const float* b_attn = (const float*)d_in[2];
  const float* W_parm = (const float*)d_in[3];
  const float* b_parm = (const float*)d_in[4];
  const float* W_proj = (const float*)d_in[5];
  const float* b_proj = (const float*)d_in[6];
  const float* w      = (const float*)d_in[7];
  const float* bb     = (const float*)d_in[8];
  float* out = (float*)d_out;

  const int M = BB * TT;        // 8192
  uint32_t* qkv     = (uint32_t*)d_ws;                  // M x 3120 (packed; p cols raw f32)
  uint32_t* wattn_t = qkv + (size_t)M * STR;            // 3120 x 1024 packed ([W_attn|W_param]^T)
  uint32_t* wproj_t = wattn_t + (size_t)3120 * 1024;    // 1024 x 1024 packed
  float*    bcat    = (float*)(wproj_t + (size_t)1024 * 1024);  // 3120 (b_attn | b_param)

  hipMemcpyAsync(bcat, b_attn, 3072 * sizeof(float), hipMemcpyDeviceToDevice, stream);
  hipMemcpyAsync(bcat + 3072, b_parm, 48 * sizeof(float), hipMemcpyDeviceToDevice, stream);

  // pre-split + transpose weights (one-time, memory-bound)
  split_transpose<<<dim3(3072 / 32, 1024 / 32), 256, 0, stream>>>(W_attn, wattn_t, 1024, 3072, 0);
  split_transpose<<<dim3(2, 1024 / 32), 256, 0, stream>>>(W_parm, wattn_t, 1024, 48, 3072);
  split_transpose<<<dim3(1024 / 32, 1024 / 32), 256, 0, stream>>>(W_proj, wproj_t, 1024, 1024, 0);

  // fused: [qkv | p] = x @ [W_attn | W_param] + [b_attn | b_param];
  // q/k rows L2-normalized in-epilogue; q/k/v packed, p raw f32.
  gemm_split<false, true, true><<<dim3(25, M / 128), 256, 0, stream>>>(
      x, CCH, wattn_t, bcat, qkv, M, STR, CCH, /*Nb=*/3120, /*Ns=*/3120, /*pklim=*/3072);
  // recurrence; writes packed LN(o) into v-slot
  titans_rec<<<BB * HH, 512, 0, stream>>>(qkv, w, bb);
  // out = o @ W_proj + b_proj
  gemm_split<true, false, false><<<dim3(CCH / 128, M / 128), 256, 0, stream>>>(
      qkv + 2048, STR, wproj_t, b_proj, out, M, CCH, CCH, /*Nb=*/1024, /*Ns=*/1024, /*pklim=*/0);
}

// Round 10
// 902.971 us; speedup vs baseline: 1.3711x; 1.0571x over previous
//
#include <hip/hip_runtime.h>
#include <cstddef>
#include <cstdint>
#include <math.h>

#define BB   4
#define TT   2048
#define CCH  1024
#define HH   16
#define DD   64
#define CSZ  16
#define NTC  128
#define EPSF 1e-5f
#define WVS  8
#define STR  3072   // qkv row stride (u32): q[0,1024) k[1024,2048) v[2048,3072); p separate

typedef __attribute__((ext_vector_type(8))) short bf16x8;
typedef __attribute__((ext_vector_type(4))) float f32x4;
typedef __attribute__((ext_vector_type(2))) float f32x2;

// Barrier that flushes LDS ops only. Global stores / register prefetch loads stay
// in flight across the barrier (guide T4); compiler still inserts vmcnt(N) before
// each use of a prefetched register.
__device__ __forceinline__ void bar_lds() {
  asm volatile("s_waitcnt lgkmcnt(0)" ::: "memory");
  __builtin_amdgcn_s_barrier();
}

// ---------- split-float helpers: f32 ≈ hi(bf16) + lo(bf16), packed (hi | lo<<16) ----------
__device__ __forceinline__ uint32_t pack_split(float f) {
  uint32_t b = __float_as_uint(f);
  uint32_t uh = (b + 0x7fffu + ((b >> 16) & 1u)) >> 16;   // RNE bf16 of f
  float fh = __uint_as_float(uh << 16);
  float r = f - fh;
  return uh | (__float_as_uint(r) & 0xffff0000u);          // lo = trunc bf16 of residual
}
__device__ __forceinline__ float unpack_f(uint32_t u) {
  return __uint_as_float(u << 16) + __uint_as_float(u & 0xffff0000u);
}

// Wave64 sum via DPP (VALU pipe).
__device__ __forceinline__ float wave_sum(float x) {
  float v = x;
  v += __int_as_float(__builtin_amdgcn_update_dpp(0, __float_as_int(v), 0x111, 0xf, 0xf, true));
  v += __int_as_float(__builtin_amdgcn_update_dpp(0, __float_as_int(v), 0x112, 0xf, 0xf, true));
  v += __int_as_float(__builtin_amdgcn_update_dpp(0, __float_as_int(v), 0x114, 0xf, 0xf, true));
  v += __int_as_float(__builtin_amdgcn_update_dpp(0, __float_as_int(v), 0x118, 0xf, 0xf, true));
  v += __int_as_float(__builtin_amdgcn_update_dpp(0, __float_as_int(v), 0x142, 0xa, 0xf, true));
  v += __int_as_float(__builtin_amdgcn_update_dpp(0, __float_as_int(v), 0x143, 0xc, 0xf, true));
  return __int_as_float(__builtin_amdgcn_readlane(__float_as_int(v), 63));
}

// Sum across a 16-lane group: quad_perm xor1, xor2, row_ror:4, row_ror:8.
__device__ __forceinline__ float red16(float x) {
  float v = x;
  v += __int_as_float(__builtin_amdgcn_update_dpp(0, __float_as_int(v), 0x0B1, 0xf, 0xf, true));
  v += __int_as_float(__builtin_amdgcn_update_dpp(0, __float_as_int(v), 0x04E, 0xf, 0xf, true));
  v += __int_as_float(__builtin_amdgcn_update_dpp(0, __float_as_int(v), 0x124, 0xf, 0xf, true));
  v += __int_as_float(__builtin_amdgcn_update_dpp(0, __float_as_int(v), 0x128, 0xf, 0xf, true));
  return v;
}

__device__ __forceinline__ float sigmoidf_(float x) {
  return 1.f / (1.f + expf(-x));
}

// ---------- transpose + split into PLANES: W (KxN f32) -> Whi/Wlo rows [rowOff, rowOff+N) ----------
__global__ __launch_bounds__(256) void split_transpose_pl(
    const float* __restrict__ W, unsigned short* __restrict__ Whi,
    unsigned short* __restrict__ Wlo, int K, int N, int rowOff) {
  __shared__ float t[32][33];
  const int n0 = blockIdx.x * 32, k0 = blockIdx.y * 32;
  const int tx = threadIdx.x & 31, ty = threadIdx.x >> 5;  // ty 0..7
#pragma unroll
  for (int i = 0; i < 4; i++) {
    int n = n0 + tx;
    t[ty + i * 8][tx] = (n < N) ? W[(size_t)(k0 + ty + i * 8) * N + n] : 0.f;
  }
  __syncthreads();
#pragma unroll
  for (int i = 0; i < 4; i++) {
    int n = n0 + ty + i * 8;
    if (n < N) {
      uint32_t ps = pack_split(t[tx][ty + i * 8]);
      size_t off = (size_t)(rowOff + n) * K + k0 + tx;
      Whi[off] = (unsigned short)(ps & 0xffffu);
      Wlo[off] = (unsigned short)(ps >> 16);
    }
  }
}

// ---------- split-bf16 MFMA GEMM: C = A @ B^T + bias ----------
// B given as hi/lo ushort planes (rows x K); rows >= Nb are zero-staged. Stores
// guarded to col < Ns. Cols >= pc0 are stored as raw f32 into Pbuf (ld 48).
// NORM: blocks with col0 < 2048 L2-normalize each 64-col head-row before packing.
// Register prefetch + lgkm-only barriers: vmem spans the K-loop barriers.
template<bool A_PACKED, bool C_PACKED, bool NORM>
__global__ __launch_bounds__(256) void gemm_split(
    const void* __restrict__ Av, int lda,
    const unsigned short* __restrict__ Bhg,
    const unsigned short* __restrict__ Blg,
    const float* __restrict__ bias,
    void* __restrict__ Cv, float* __restrict__ Pbuf,
    int M, int ldc, int K, int Nb, int Ns, int pc0) {
  __shared__ unsigned short Ahi[128][40];
  __shared__ unsigned short Alo[128][40];
  __shared__ unsigned short Bhi[128][40];
  __shared__ unsigned short Blo[128][40];

  const int tid = threadIdx.x;
  const int row0 = blockIdx.y * 128;
  const int col0 = blockIdx.x * 128;
  const int wv = tid >> 6;
  const int l  = tid & 63;
  const int wr = wv >> 1, wc = wv & 1;
  const int lrow = l & 15;
  const int kgrp = (l >> 4) * 8;

  const int sr = tid >> 1;
  const int sk = (tid & 1) * 16;

  f32x4 acc[4][4];
#pragma unroll
  for (int i = 0; i < 4; i++)
#pragma unroll
    for (int j = 0; j < 4; j++) acc[i][j] = (f32x4){0.f, 0.f, 0.f, 0.f};

  uint4 pa[4];    // A_PACKED: 16 packed u32
  float4 pf[4];   // !A_PACKED: 16 floats
  uint4 pbh[2], pbl[2];   // B planes: 32B hi + 32B lo

  auto load_tile = [&](int k0) {
    if (A_PACKED) {
      const uint32_t* Ap = (const uint32_t*)Av + (size_t)(row0 + sr) * lda + k0 + sk;
#pragma unroll
      for (int i = 0; i < 4; i++) pa[i] = *(const uint4*)(Ap + i * 4);
    } else {
      const float* Ap = (const float*)Av + (size_t)(row0 + sr) * lda + k0 + sk;
#pragma unroll
      for (int i = 0; i < 4; i++) pf[i] = *(const float4*)(Ap + i * 4);
    }
    if (col0 + sr < Nb) {
      const unsigned short* bh = Bhg + (size_t)(col0 + sr) * K + k0 + sk;
      const unsigned short* bl = Blg + (size_t)(col0 + sr) * K + k0 + sk;
      pbh[0] = *(const uint4*)bh;  pbh[1] = *(const uint4*)(bh + 8);
      pbl[0] = *(const uint4*)bl;  pbl[1] = *(const uint4*)(bl + 8);
    } else {
      pbh[0] = pbh[1] = pbl[0] = pbl[1] = make_uint4(0u, 0u, 0u, 0u);
    }
  };

  auto commit_tile = [&]() {
    uint32_t hp[8], lp[8];
    if (A_PACKED) {
      uint32_t u[16];
#pragma unroll
      for (int i = 0; i < 4; i++) *(uint4*)&u[i * 4] = pa[i];
#pragma unroll
      for (int j = 0; j < 8; j++) {
        hp[j] = (u[2 * j] & 0xffffu) | (u[2 * j + 1] << 16);
        lp[j] = (u[2 * j] >> 16) | (u[2 * j + 1] & 0xffff0000u);
      }
    } else {
      float f[16];
#pragma unroll
      for (int i = 0; i < 4; i++) *(float4*)&f[i * 4] = pf[i];
      uint32_t uh[16], ulr[16];
#pragma unroll
      for (int j = 0; j < 16; j++) {
        uint32_t b = __float_as_uint(f[j]);
        uint32_t h = (b + 0x7fffu + ((b >> 16) & 1u)) >> 16;
        uh[j] = h;
        ulr[j] = __float_as_uint(f[j] - __uint_as_float(h << 16));
      }
#pragma unroll
      for (int j = 0; j < 8; j++) {
        hp[j] = uh[2 * j] | (uh[2 * j + 1] << 16);
        lp[j] = (ulr[2 * j] >> 16) | (ulr[2 * j + 1] & 0xffff0000u);
      }
    }
    *(uint4*)&Ahi[sr][sk]     = *(uint4*)&hp[0];
    *(uint4*)&Ahi[sr][sk + 8] = *(uint4*)&hp[4];
    *(uint4*)&Alo[sr][sk]     = *(uint4*)&lp[0];
    *(uint4*)&Alo[sr][sk + 8] = *(uint4*)&lp[4];
    // B: pure plane copies (no VALU transform)
    *(uint4*)&Bhi[sr][sk]     = pbh[0];
    *(uint4*)&Bhi[sr][sk + 8] = pbh[1];
    *(uint4*)&Blo[sr][sk]     = pbl[0];
    *(uint4*)&Blo[sr][sk + 8] = pbl[1];
  };

  load_tile(0);
  for (int k0 = 0; k0 < K; k0 += 32) {
    commit_tile();
    bar_lds();                               // flush ds_writes; vmem stays in flight
    if (k0 + 32 < K) load_tile(k0 + 32);     // spans the next barrier

    bf16x8 bh[4], bl[4];
#pragma unroll
    for (int j = 0; j < 4; j++) {
      bh[j] = *(const bf16x8*)&Bhi[wc * 64 + j * 16 + lrow][kgrp];
      bl[j] = *(const bf16x8*)&Blo[wc * 64 + j * 16 + lrow][kgrp];
    }
#pragma unroll
    for (int i = 0; i < 4; i++) {
      bf16x8 ah = *(const bf16x8*)&Ahi[wr * 64 + i * 16 + lrow][kgrp];
      bf16x8 al = *(const bf16x8*)&Alo[wr * 64 + i * 16 + lrow][kgrp];
#pragma unroll
      for (int j = 0; j < 4; j++) {
        acc[i][j] = __builtin_amdgcn_mfma_f32_16x16x32_bf16(ah, bh[j], acc[i][j], 0, 0, 0);
        acc[i][j] = __builtin_amdgcn_mfma_f32_16x16x32_bf16(ah, bl[j], acc[i][j], 0, 0, 0);
        acc[i][j] = __builtin_amdgcn_mfma_f32_16x16x32_bf16(al, bh[j], acc[i][j], 0, 0, 0);
      }
    }
    bar_lds();
  }

  // ---- epilogue: C/D layout col=lane&15, row=(lane>>4)*4+reg ----
  const int crow4 = (l >> 4) * 4;
  if (NORM && col0 < 2048) {
    // q/k rows: normalize each head-row (64 cols) in-register.
    float bj[4];
#pragma unroll
    for (int j = 0; j < 4; j++) bj[j] = bias[col0 + wc * 64 + j * 16 + lrow];
#pragma unroll
    for (int i = 0; i < 4; i++) {
#pragma unroll
      for (int r = 0; r < 4; r++) {
        float vals[4];
        float ss = 0.f;
#pragma unroll
        for (int j = 0; j < 4; j++) {
          vals[j] = acc[i][j][r] + bj[j];
          ss += vals[j] * vals[j];
        }
        ss = red16(ss);
        float sc = 1.f / fmaxf(sqrtf(ss), 1e-12f);
        const int rowb = row0 + wr * 64 + i * 16 + crow4 + r;
#pragma unroll
        for (int j = 0; j < 4; j++) {
          const int col = col0 + wc * 64 + j * 16 + lrow;
          ((uint32_t*)Cv)[(size_t)rowb * ldc + col] = pack_split(vals[j] * sc);
        }
      }
    }
  } else {
#pragma unroll
    for (int i = 0; i < 4; i++) {
#pragma unroll
      for (int j = 0; j < 4; j++) {
        const int col = col0 + wc * 64 + j * 16 + lrow;
        const float bv = (col < Ns) ? bias[col] : 0.f;
        const int rowb = row0 + wr * 64 + i * 16 + crow4;
#pragma unroll
        for (int r = 0; r < 4; r++) {
          float v = acc[i][j][r] + bv;
          if (col < Ns) {
            if (col >= pc0) {
              Pbuf[(size_t)(rowb + r) * 48 + (col - pc0)] = v;          // raw f32 params
            } else if (C_PACKED) {
              ((uint32_t*)Cv)[(size_t)(rowb + r) * ldc + col] = pack_split(v);
            } else {
              ((float*)Cv)[(size_t)(rowb + r) * ldc + col] = v;
            }
          }
        }
      }
    }
  }
}

// Titans recurrence (r8-proven structure, 539 µs). One block per (b,h), 512 threads
// = 8 waves x 8 S-rows; packed-fp32 (pk_fma) hot loops; lgkm-only barriers. q/k
// arrive L2-normalized (fused in GEMM epilogue); p compact (M x 48 f32, aligned).
__global__ __launch_bounds__(512) void titans_rec(
    uint32_t* __restrict__ qkv, const float* __restrict__ p,
    const float* __restrict__ w, const float* __restrict__ bparm) {
  const int bh = blockIdx.x;
  const int b = bh >> 4;
  const int h = bh & 15;
  const int tid = threadIdx.x;
  const int wv = tid >> 6;   // 0..7
  const int l = tid & 63;

  __shared__ float k_s[2][CSZ][DD];
  __shared__ float q_s[2][CSZ][DD];
  __shared__ float v_s[CSZ][DD];
  __shared__ float dkh_s[CSZ][DD];
  __shared__ float part[2][WVS][CSZ][DD];
  __shared__ float4 prm_s[2][CSZ];

  f32x2 S2[4], M2[4];
#pragma unroll
  for (int r = 0; r < 4; r++) { S2[r] = (f32x2){0.f, 0.f}; M2[r] = (f32x2){0.f, 0.f}; }

  const float w_l = w[h * DD + l];
  const float b_l = bparm[h * DD + l];

  uint32_t* qbase = qkv + (size_t)(b * TT) * STR + h * DD;
  const float* pbase = p + (size_t)(b * TT) * 48 + h * 3;

  uint32_t rq[2], rk[2], rv[2];
  float rp0 = 0.f, rp1 = 0.f, rp2 = 0.f;
  // ---- prologue: load + commit chunk 0; load chunk 1 into regs ----
  {
#pragma unroll
    for (int i = 0; i < 2; i++) {
      const int row = wv + i * 8;
      size_t roff = (size_t)row * STR + l;
      q_s[0][row][l] = unpack_f(qbase[roff]);
      k_s[0][row][l] = unpack_f(qbase[roff + 1024]);
      v_s[row][l]    = unpack_f(qbase[roff + 2048]);
    }
    if (tid < CSZ) {
      const float* pp = pbase + (size_t)tid * 48;
      prm_s[0][tid] = make_float4(sigmoidf_(pp[0]), sigmoidf_(pp[1]), sigmoidf_(pp[2]), 0.f);
    }
#pragma unroll
    for (int i = 0; i < 2; i++) {
      size_t roff = (size_t)(CSZ + wv + i * 8) * STR + l;
      rq[i] = qbase[roff];
      rk[i] = qbase[roff + 1024];
      rv[i] = qbase[roff + 2048];
    }
    if (tid < CSZ) {
      const float* pp = pbase + (size_t)(CSZ + tid) * 48;
      rp0 = pp[0]; rp1 = pp[1]; rp2 = pp[2];
    }
  }
  bar_lds();

  for (int nt = 0; nt < NTC; nt++) {
    const int buf = nt & 1;
    float (*partw)[CSZ][DD] = part[buf];       // this chunk's kh, then po
    float (*partr)[CSZ][DD] = part[buf ^ 1];   // previous chunk's po

    // ---- phase A: deferred o/LN/store of chunk nt-1, then kh partials (packed) ----
    if (nt > 0) {
#pragma unroll
      for (int i = 0; i < 2; i++) {
        const int t = wv + i * 8;
        float o = 0.f;
#pragma unroll
        for (int ww = 0; ww < WVS; ww++) o += partr[ww][t][l];
        float mu = wave_sum(o) * (1.f / 64.f);
        float xc = o - mu;
        float var = wave_sum(xc * xc) * (1.f / 64.f);
        float rstd = rsqrtf(var + EPSF);
        float y = xc * rstd * w_l + b_l;
        qbase[(size_t)((nt - 1) * CSZ + t) * STR + 2048 + l] = pack_split(y);
      }
    }
#pragma unroll
    for (int c = 0; c < CSZ; c++) {
      const f32x2* kp2 = (const f32x2*)&k_s[buf][c][wv * 8];
      f32x2 a2;
      a2 = kp2[0] * S2[0];
      a2 = kp2[1] * S2[1] + a2;
      a2 = kp2[2] * S2[2] + a2;
      a2 = kp2[3] * S2[3] + a2;
      partw[wv][c][l] = a2.x + a2.y;
    }
    bar_lds();

    // ---- phase B: LN fwd + bwd — two token rows per wave ----
#pragma unroll
    for (int i = 0; i < 2; i++) {
      const int c = wv + i * 8;
      float kh = 0.f;
#pragma unroll
      for (int ww = 0; ww < WVS; ww++) kh += partw[ww][c][l];
      float mu = wave_sum(kh) * (1.f / 64.f);
      float xc = kh - mu;
      float var = wave_sum(xc * xc) * (1.f / 64.f);
      float rstd = rsqrtf(var + EPSF);
      float xhat = xc * rstd;
      float y = xhat * w_l + b_l;
      float dy = 2.f * (y - v_s[c][l]);
      float wdy = dy * w_l;
      float c1 = wave_sum(xhat * wdy) * (1.f / 64.f);
      float c2 = wave_sum(wdy) * (1.f / 64.f);
      dkh_s[c][l] = (wdy - xhat * c1 - c2) * rstd;
    }
    bar_lds();

    // ---- phase C: commit next tiles, issue prefetch, token scan (packed) ----
    if (nt + 1 < NTC) {
#pragma unroll
      for (int i = 0; i < 2; i++) {
        const int row = wv + i * 8;
        k_s[buf ^ 1][row][l] = unpack_f(rk[i]);
        q_s[buf ^ 1][row][l] = unpack_f(rq[i]);
        v_s[row][l] = unpack_f(rv[i]);
      }
      if (tid < CSZ)
        prm_s[buf ^ 1][tid] = make_float4(sigmoidf_(rp0), sigmoidf_(rp1), sigmoidf_(rp2), 0.f);
    }
    if (nt + 2 < NTC) {
#pragma unroll
      for (int i = 0; i < 2; i++) {
        size_t roff = (size_t)((nt + 2) * CSZ + wv + i * 8) * STR + l;
        rq[i] = qbase[roff];
        rk[i] = qbase[roff + 1024];
        rv[i] = qbase[roff + 2048];
      }
      if (tid < CSZ) {
        const float* pp = pbase + (size_t)((nt + 2) * CSZ + tid) * 48;
        rp0 = pp[0]; rp1 = pp[1]; rp2 = pp[2];
      }
    }
#pragma unroll
    for (int t = 0; t < CSZ; t++) {
      float4 prm = prm_s[buf][t];
      float a = prm.x * dkh_s[t][l];
      const f32x2 na2 = (f32x2){-a, -a};
      const f32x2 et2 = (f32x2){prm.z, prm.z};
      const f32x2 be2 = (f32x2){1.f - prm.y, 1.f - prm.y};
      const f32x2* kp2 = (const f32x2*)&k_s[buf][t][wv * 8];
      const f32x2* qp2 = (const f32x2*)&q_s[buf][t][wv * 8];
      f32x2 po2 = (f32x2){0.f, 0.f};
#pragma unroll
      for (int pq = 0; pq < 4; pq++) {
        M2[pq] = et2 * M2[pq] + na2 * kp2[pq];   // pk_mul + pk_fma
        S2[pq] = be2 * S2[pq] + M2[pq];          // pk_fma
        po2    = qp2[pq] * S2[pq] + po2;         // pk_fma
      }
      partw[wv][t][l] = po2.x + po2.y;
    }
    bar_lds();
  }

  // ---- epilogue: deferred D for the last chunk ----
  {
    float (*partr)[CSZ][DD] = part[(NTC - 1) & 1];
#pragma unroll
    for (int i = 0; i < 2; i++) {
      const int t = wv + i * 8;
      float o = 0.f;
#pragma unroll
      for (int ww = 0; ww < WVS; ww++) o += partr[ww][t][l];
      float mu = wave_sum(o) * (1.f / 64.f);
      float xc = o - mu;
      float var = wave_sum(xc * xc) * (1.f / 64.f);
      float rstd = rsqrtf(var + EPSF);
      float y = xc * rstd * w_l + b_l;
      qbase[(size_t)((NTC - 1) * CSZ + t) * STR + 2048 + l] = pack_split(y);
    }
  }
}

extern "C" void kernel_launch(void* const* d_in, const int* in_sizes, int n_in,
                              void* d_out, int out_size, void* d_ws, size_t ws_size,
                              hipStream_t stream) {
  const float* x      = (const float*)d_in[0];
  const float* W_attn = (const float*)d_in[1];
  const float* b_attn = (const float*)d_in[2];
  const float* W_parm = (const float*)d_in[3];
  const float* b_parm = (const float*)d_in[4];
  const float* W_proj = (const float*)d_in[5];
  const float* b_proj = (const float*)d_in[6];
  const float* w      = (const float*)d_in[7];
  const float* bb     = (const float*)d_in[8];
  float* out = (float*)d_out;

  const int M = BB * TT;        // 8192
  uint32_t* qkv = (uint32_t*)d_ws;                           // M x 3072 packed u32 (aligned rows)
  float* pbf = (float*)(qkv + (size_t)M * STR);              // M x 48 f32 (compact params)
  unsigned short* wattn_hi = (unsigned short*)(pbf + (size_t)M * 48);   // 3120 x 1024
  unsigned short* wattn_lo = wattn_hi + (size_t)3120 * 1024;
  unsigned short* wproj_hi = wattn_lo + (size_t)3120 * 1024;            // 1024 x 1024
  unsigned short* wproj_lo = wproj_hi + (size_t)1024 * 1024;
  float* bcat = (float*)(wproj_lo + (size_t)1024 * 1024);               // 3120 f32

  hipMemcpyAsync(bcat, b_attn, 3072 * sizeof(float), hipMemcpyDeviceToDevice, stream);
  hipMemcpyAsync(bcat + 3072, b_parm, 48 * sizeof(float), hipMemcpyDeviceToDevice, stream);

  // pre-split + transpose weights into hi/lo planes (one-time, memory-bound)
  split_transpose_pl<<<dim3(3072 / 32, 1024 / 32), 256, 0, stream>>>(W_attn, wattn_hi, wattn_lo, 1024, 3072, 0);
  split_transpose_pl<<<dim3(2, 1024 / 32), 256, 0, stream>>>(W_parm, wattn_hi, wattn_lo, 1024, 48, 3072);
  split_transpose_pl<<<dim3(1024 / 32, 1024 / 32), 256, 0, stream>>>(W_proj, wproj_hi, wproj_lo, 1024, 1024, 0);

  // fused: [qkv | p] = x @ [W_attn | W_param] + bias; q/k L2-normalized in-epilogue;
  // q/k/v packed into qkv, p raw f32 into pbf.
  gemm_split<false, true, true><<<dim3(25, M / 128), 256, 0, stream>>>(
      x, CCH, wattn_hi, wattn_lo, bcat, qkv, pbf, M, STR, CCH,
      /*Nb=*/3120, /*Ns=*/3120, /*pc0=*/3072);
  // recurrence; writes packed LN(o) into v-slot
  titans_rec<<<BB * HH, 512, 0, stream>>>(qkv, pbf, w, bb);
  // out = o @ W_proj + b_proj
  gemm_split<true, false, false><<<dim3(CCH / 128, M / 128), 256, 0, stream>>>(
      qkv + 2048, STR, wproj_hi, wproj_lo, b_proj, out, nullptr, M, CCH, CCH,
      /*Nb=*/1024, /*Ns=*/1024, /*pc0=*/1 << 30);
}